// Round 13
// baseline (338.155 us; speedup 1.0000x reference)
//
#include <hip/hip_runtime.h>
#include <stdint.h>

#define T_TOKENS 2048
#define DM 1024
#define DF 4096
#define NEXP 8
#define NSLOTS (T_TOKENS * 2)

typedef __bf16 bf16x8 __attribute__((ext_vector_type(8)));
typedef float f32x4 __attribute__((ext_vector_type(4)));

__device__ __forceinline__ ushort f2bf(float f) {
    union { float f; uint32_t u; } v; v.f = f;
    uint32_t r = v.u + 0x7FFFu + ((v.u >> 16) & 1u);
    return (ushort)(r >> 16);
}

__device__ __forceinline__ void gload16(const ushort* g, ushort* l) {
    __builtin_amdgcn_global_load_lds(
        (const __attribute__((address_space(1))) uint32_t*)g,
        (__attribute__((address_space(3))) uint32_t*)l,
        16, 0, 0);
}

// ---------------- init: zero expert counters ----------------
__global__ void init_cnt(uint32_t* cnt) {
    if (threadIdx.x < NEXP) cnt[threadIdx.x] = 0;
}

// ---------------- exclusive prefix over the 8 counts ----------------
__global__ void prefix_offs(const uint32_t* __restrict__ cnt,
                            uint32_t* __restrict__ offs)
{
    if (threadIdx.x == 0) {
        uint32_t a = 0;
#pragma unroll
        for (int e = 0; e < NEXP; ++e) { offs[e] = a; a += cnt[e]; }
        offs[NEXP] = a;
    }
}

// ====== prep: gate_route [0,512) | convert_x [512,2560) ======================
__global__ __launch_bounds__(256) void prep_kernel(
    const float* __restrict__ x, const float* __restrict__ gw,
    const float* __restrict__ gb,
    uint32_t* __restrict__ route, uint32_t* __restrict__ cnt,
    float* __restrict__ prob, uint32_t* __restrict__ epk,
    ushort* __restrict__ xb)
{
    const int bx = blockIdx.x;
    const int tid = threadIdx.x;

    if (bx < 512) {
        // ---- gate + route: one wave per token ----
        const int w = tid >> 6;
        const int lane = tid & 63;
        const int t = bx * 4 + w;
        float acc[NEXP];
#pragma unroll
        for (int e = 0; e < NEXP; ++e) acc[e] = 0.f;
        const float* xr = x + (size_t)t * DM;
#pragma unroll
        for (int j = 0; j < DM / 64; ++j) {
            const int d = j * 64 + lane;
            const float xv = xr[d];
            const float* g = gw + (size_t)d * NEXP;
#pragma unroll
            for (int e = 0; e < NEXP; ++e) acc[e] += xv * g[e];
        }
#pragma unroll
        for (int e = 0; e < NEXP; ++e) {
#pragma unroll
            for (int off = 32; off > 0; off >>= 1)
                acc[e] += __shfl_xor(acc[e], off);
            acc[e] += gb[e];
        }
        if (lane == 0) {
            int e0 = 0; float v0 = acc[0];
#pragma unroll
            for (int e = 1; e < NEXP; ++e) if (acc[e] > v0) { v0 = acc[e]; e0 = e; }
            int e1 = -1; float v1 = -1e30f;
#pragma unroll
            for (int e = 0; e < NEXP; ++e) if (e != e0 && acc[e] > v1) { v1 = acc[e]; e1 = e; }
            const float ex = expf(v1 - v0);
            const float inv = 1.f / (1.f + ex);
            prob[t * 2 + 0] = inv;
            prob[t * 2 + 1] = ex * inv;
            uint32_t pos = atomicAdd(&cnt[e0], 1u);
            route[e0 * T_TOKENS + pos] = (uint32_t)(t * 2);
            epk[t * 2] = ((uint32_t)e0 << 16) | pos;
            pos = atomicAdd(&cnt[e1], 1u);
            route[e1 * T_TOKENS + pos] = (uint32_t)(t * 2 + 1);
            epk[t * 2 + 1] = ((uint32_t)e1 << 16) | pos;
        }
    } else {
        // ---- x fp32 -> bf16 ----
        const int i = ((bx - 512) * 256 + tid) * 4;
        const float4 v = *reinterpret_cast<const float4*>(x + i);
        ushort4 o;
        o.x = f2bf(v.x); o.y = f2bf(v.y); o.z = f2bf(v.z); o.w = f2bf(v.w);
        *reinterpret_cast<ushort4*>(xb + i) = o;
    }
}

// ====== grouped expert GEMM v12: fp32-B in-GEMM staging, no transpose ========
// A: bf16 (gload16 direct-to-LDS, [128][32] chunk-XOR swizzle on source+read).
// B: native fp32 W [E][KD][ND] staged per-iter: 4x float4 coalesced loads
//    (4 consecutive k-rows x 4 n), f2bf in regs, 4x ushort4 writes along-k
//    into [128][40]-padded bf16 LDS (16B-aligned rows, frag reads ~free).
// 2-phase double buffer: issue(t+1) -> compute(t) -> cvt+write(t+1) -> sync.
// XCD-chunked bijective swizzle: expert-per-XCD, mt fastest (R10, 5x FETCH win).
template<int KD, int ND, bool FIRST, int SPLIT, int NMT, int NT>
__global__ __launch_bounds__(256, 4) void moe_gemm12(
    const ushort* __restrict__ Abuf,
    const float* __restrict__ W,
    const float* __restrict__ bias,
    const uint32_t* __restrict__ route,
    const uint32_t* __restrict__ cnt,
    const uint32_t* __restrict__ offs,
    const float* __restrict__ prob,
    ushort* __restrict__ hout,
    float* __restrict__ yout)
{
    const int bx0 = blockIdx.x;
    const int cpx = (NEXP * NMT * NT) >> 3;
    const int wk  = (bx0 & 7) * cpx + (bx0 >> 3);
    const int e   = wk / (NMT * NT);
    const int r   = wk % (NMT * NT);
    const int nt  = r / NMT;
    const int mt  = r % NMT;
    const uint32_t cntE = cnt[e];
    const int m0 = mt * 128;
    if ((uint32_t)m0 >= cntE) return;
    const uint32_t hb = offs[e];
    const int n0 = nt * 128;
    const int z  = (SPLIT > 1) ? (int)blockIdx.z : 0;
    const int kbeg = z * (KD / SPLIT);
    const int niter = (KD / SPLIT) / 32;

    __shared__ ushort As[2][128 * 32];     // 16 KB
    __shared__ ushort Bs[2][128 * 40];     // 20 KB (+8 ushort row pad)
    __shared__ uint32_t s_route[128];
    __shared__ float s_p[128];

    const int tid = threadIdx.x;
    if (FIRST) {
        if (tid < 128) {
            const uint32_t idx = (uint32_t)(m0 + tid);
            const uint32_t s = (idx < cntE) ? route[e * T_TOKENS + idx] : 0u;
            s_route[tid] = s;
            s_p[tid] = prob[s];
        }
        __syncthreads();
    }

    const int w = tid >> 6, l = tid & 63;

    // ---- A staging map (R10): 2 gload16/thread, inverse chunk-XOR on source
    const ushort* asrc[2];
#pragma unroll
    for (int i = 0; i < 2; ++i) {
        const int chunk = (w * 2 + i) * 64 + l;   // 0..511
        const int row = chunk >> 2;               // 0..127
        const int c   = chunk & 3;
        const int cs  = c ^ ((row >> 1) & 3);
        size_t arow;
        if (FIRST) arow = (size_t)(s_route[row] >> 1);
        else       arow = (size_t)(hb + m0 + row);
        asrc[i] = Abuf + arow * KD + cs * 8 + kbeg;
    }

    // ---- B staging map: c4 = n-quad (0..31), kq = k-quad (0..7)
    const int c4 = tid & 31;
    const int kq = tid >> 5;
    const float* wbase = W + ((size_t)e * KD + kbeg + (size_t)kq * 4) * ND
                         + n0 + c4 * 4;
    ushort* const bdst0 = &Bs[0][0];

    f32x4 acc[4][4];
#pragma unroll
    for (int i = 0; i < 4; ++i)
#pragma unroll
        for (int j = 0; j < 4; ++j) acc[i][j] = (f32x4){0.f, 0.f, 0.f, 0.f};

    const int q = l & 15, g = l >> 4;
    const int wm = w >> 1, wn = w & 1;

    // A frag offsets: swizzled within [128][32]; B frag offsets: linear [128][40]
    int aoff[4], boff[4];
#pragma unroll
    for (int mi = 0; mi < 4; ++mi) {
        int row = wm * 64 + mi * 16 + q;
        aoff[mi] = row * 64 + (g ^ ((row >> 1) & 3)) * 16;          // bytes
        row = wn * 64 + mi * 16 + q;
        boff[mi] = row * 40 + g * 8;                                 // ushorts
    }

    ushort* const abase0 = &As[0][0];

    // ---- prologue: stage tile 0 into buf 0
    {
        float4 b0 = *reinterpret_cast<const float4*>(wbase + (size_t)0 * ND);
        float4 b1 = *reinterpret_cast<const float4*>(wbase + (size_t)1 * ND);
        float4 b2 = *reinterpret_cast<const float4*>(wbase + (size_t)2 * ND);
        float4 b3 = *reinterpret_cast<const float4*>(wbase + (size_t)3 * ND);
#pragma unroll
        for (int i = 0; i < 2; ++i) gload16(asrc[i], abase0 + (w * 2 + i) * 512);
        const int bn = c4 * 4;
        ushort4 o0 = { f2bf(b0.x), f2bf(b1.x), f2bf(b2.x), f2bf(b3.x) };
        ushort4 o1 = { f2bf(b0.y), f2bf(b1.y), f2bf(b2.y), f2bf(b3.y) };
        ushort4 o2 = { f2bf(b0.z), f2bf(b1.z), f2bf(b2.z), f2bf(b3.z) };
        ushort4 o3 = { f2bf(b0.w), f2bf(b1.w), f2bf(b2.w), f2bf(b3.w) };
        *reinterpret_cast<ushort4*>(bdst0 + (bn + 0) * 40 + kq * 4) = o0;
        *reinterpret_cast<ushort4*>(bdst0 + (bn + 1) * 40 + kq * 4) = o1;
        *reinterpret_cast<ushort4*>(bdst0 + (bn + 2) * 40 + kq * 4) = o2;
        *reinterpret_cast<ushort4*>(bdst0 + (bn + 3) * 40 + kq * 4) = o3;
    }
    __syncthreads();

    int cur = 0;
    for (int t = 0; t < niter; ++t) {
        float4 b0, b1, b2, b3;
        const bool pf = (t + 1 < niter);
        if (pf) {
            const size_t k1 = (size_t)(t + 1) * 32;
            b0 = *reinterpret_cast<const float4*>(wbase + (k1 + 0) * ND);
            b1 = *reinterpret_cast<const float4*>(wbase + (k1 + 1) * ND);
            b2 = *reinterpret_cast<const float4*>(wbase + (k1 + 2) * ND);
            b3 = *reinterpret_cast<const float4*>(wbase + (k1 + 3) * ND);
            ushort* ad = abase0 + (cur ^ 1) * (128 * 32) + (w * 2) * 512;
#pragma unroll
            for (int i = 0; i < 2; ++i) gload16(asrc[i] + k1, ad + i * 512);
        }

        // ---- compute current tile
        const char* Ab = (const char*)(abase0 + cur * (128 * 32));
        const ushort* Bb = bdst0 + cur * (128 * 40);
        bf16x8 af[4], bv[4];
#pragma unroll
        for (int mi = 0; mi < 4; ++mi)
            af[mi] = *reinterpret_cast<const bf16x8*>(Ab + aoff[mi]);
#pragma unroll
        for (int ni = 0; ni < 4; ++ni)
            bv[ni] = *reinterpret_cast<const bf16x8*>(Bb + boff[ni]);
        __builtin_amdgcn_s_setprio(1);
#pragma unroll
        for (int mi = 0; mi < 4; ++mi)
#pragma unroll
            for (int ni = 0; ni < 4; ++ni)
                acc[mi][ni] = __builtin_amdgcn_mfma_f32_16x16x32_bf16(
                    af[mi], bv[ni], acc[mi][ni], 0, 0, 0);
        __builtin_amdgcn_s_setprio(0);
        __builtin_amdgcn_sched_barrier(0);

        if (pf) {
            // convert + write B(t+1) into the other buffer (compiler inserts
            // the vmcnt wait for b0..b3 here; load latency covered by MFMA)
            ushort* bd = bdst0 + (cur ^ 1) * (128 * 40);
            const int bn = c4 * 4;
            ushort4 o0 = { f2bf(b0.x), f2bf(b1.x), f2bf(b2.x), f2bf(b3.x) };
            ushort4 o1 = { f2bf(b0.y), f2bf(b1.y), f2bf(b2.y), f2bf(b3.y) };
            ushort4 o2 = { f2bf(b0.z), f2bf(b1.z), f2bf(b2.z), f2bf(b3.z) };
            ushort4 o3 = { f2bf(b0.w), f2bf(b1.w), f2bf(b2.w), f2bf(b3.w) };
            *reinterpret_cast<ushort4*>(bd + (bn + 0) * 40 + kq * 4) = o0;
            *reinterpret_cast<ushort4*>(bd + (bn + 1) * 40 + kq * 4) = o1;
            *reinterpret_cast<ushort4*>(bd + (bn + 2) * 40 + kq * 4) = o2;
            *reinterpret_cast<ushort4*>(bd + (bn + 3) * 40 + kq * 4) = o3;
        }
        __syncthreads();   // drains vmcnt (A glds) + lgkm (B writes) for all
        cur ^= 1;
    }

    // ---- epilogue
#pragma unroll
    for (int mi = 0; mi < 4; ++mi) {
#pragma unroll
        for (int ni = 0; ni < 4; ++ni) {
            const int gcol = n0 + wn * 64 + ni * 16 + q;
#pragma unroll
            for (int j = 0; j < 4; ++j) {
                const int row = wm * 64 + mi * 16 + g * 4 + j;
                if ((uint32_t)(m0 + row) < cntE) {
                    const size_t grow = (size_t)(hb + m0 + row);
                    if (FIRST) {
                        float v = acc[mi][ni][j] + bias[e * ND + gcol];
                        v = fmaxf(v, 0.f) * s_p[row];
                        hout[grow * ND + gcol] = f2bf(v);
                    } else {
                        yout[((size_t)z * NSLOTS + grow) * ND + gcol] = acc[mi][ni][j];
                    }
                }
            }
        }
    }
}

// ------- combine: out[t] = p0*b2[e0] + p1*b2[e1] + sum_z (yc[z][r0]+yc[z][r1])
__global__ __launch_bounds__(256) void combine5(
    const float* __restrict__ yc, const uint32_t* __restrict__ epk,
    const uint32_t* __restrict__ offs, const float* __restrict__ prob,
    const float* __restrict__ b2, float* __restrict__ out)
{
    const int gid = blockIdx.x * 256 + threadIdx.x;
    const int t = gid >> 8;
    const int dq = gid & 255;
    const uint32_t p0 = epk[2 * t], p1 = epk[2 * t + 1];
    const uint32_t e0 = p0 >> 16, e1 = p1 >> 16;
    const uint32_t r0 = offs[e0] + (p0 & 0xFFFFu);
    const uint32_t r1 = offs[e1] + (p1 & 0xFFFFu);
    const float w0 = prob[2 * t], w1 = prob[2 * t + 1];
    const float4 bb0 = reinterpret_cast<const float4*>(b2 + (size_t)e0 * DM)[dq];
    const float4 bb1 = reinterpret_cast<const float4*>(b2 + (size_t)e1 * DM)[dq];
    float4 o = { w0 * bb0.x + w1 * bb1.x, w0 * bb0.y + w1 * bb1.y,
                 w0 * bb0.z + w1 * bb1.z, w0 * bb0.w + w1 * bb1.w };
    const float4* Y = reinterpret_cast<const float4*>(yc);
#pragma unroll
    for (int zz = 0; zz < 4; ++zz) {
        const float4 a = Y[((size_t)zz * NSLOTS + r0) * 256 + dq];
        const float4 b = Y[((size_t)zz * NSLOTS + r1) * 256 + dq];
        o.x += a.x + b.x; o.y += a.y + b.y; o.z += a.z + b.z; o.w += a.w + b.w;
    }
    reinterpret_cast<float4*>(out)[gid] = o;
}

// ================= fallback path (round-1, works in ~55 MB ws) =================
__global__ __launch_bounds__(256) void gate_route_fb(
    const float* __restrict__ x, const float* __restrict__ gw,
    const float* __restrict__ gb,
    uint32_t* __restrict__ route, uint32_t* __restrict__ cnt,
    float* __restrict__ prob)
{
    const int w = threadIdx.x >> 6;
    const int lane = threadIdx.x & 63;
    const int t = blockIdx.x * 4 + w;
    float acc[NEXP];
#pragma unroll
    for (int e = 0; e < NEXP; ++e) acc[e] = 0.f;
    const float* xr = x + (size_t)t * DM;
#pragma unroll
    for (int j = 0; j < DM / 64; ++j) {
        const int d = j * 64 + lane;
        const float xv = xr[d];
        const float* g = gw + (size_t)d * NEXP;
#pragma unroll
        for (int e = 0; e < NEXP; ++e) acc[e] += xv * g[e];
    }
#pragma unroll
    for (int e = 0; e < NEXP; ++e) {
#pragma unroll
        for (int off = 32; off > 0; off >>= 1)
            acc[e] += __shfl_xor(acc[e], off);
        acc[e] += gb[e];
    }
    if (lane == 0) {
        int e0 = 0; float v0 = acc[0];
#pragma unroll
        for (int e = 1; e < NEXP; ++e) if (acc[e] > v0) { v0 = acc[e]; e0 = e; }
        int e1 = -1; float v1 = -1e30f;
#pragma unroll
        for (int e = 0; e < NEXP; ++e) if (e != e0 && acc[e] > v1) { v1 = acc[e]; e1 = e; }
        const float ex = expf(v1 - v0);
        const float inv = 1.f / (1.f + ex);
        prob[t * 2 + 0] = inv;
        prob[t * 2 + 1] = ex * inv;
        uint32_t pos = atomicAdd(&cnt[e0], 1u);
        route[e0 * T_TOKENS + pos] = (uint32_t)(t * 2);
        pos = atomicAdd(&cnt[e1], 1u);
        route[e1 * T_TOKENS + pos] = (uint32_t)(t * 2 + 1);
    }
}

__global__ __launch_bounds__(256) void convert_x_fb(const float* __restrict__ x,
                                                    ushort* __restrict__ xb)
{
    const int i = (blockIdx.x * 256 + threadIdx.x) * 4;
    const float4 v = *reinterpret_cast<const float4*>(x + i);
    ushort4 o;
    o.x = f2bf(v.x); o.y = f2bf(v.y); o.z = f2bf(v.z); o.w = f2bf(v.w);
    *reinterpret_cast<ushort4*>(xb + i) = o;
}

template<int KD, int ND, bool FIRST>
__global__ __launch_bounds__(256) void moe_gemm_v1(
    const ushort* __restrict__ Abuf, const float* __restrict__ W,
    const float* __restrict__ bias, const uint32_t* __restrict__ route,
    const uint32_t* __restrict__ cnt, const float* __restrict__ prob,
    ushort* __restrict__ hout, float* __restrict__ yout)
{
    const int e = blockIdx.x >> 4;
    const int mt = blockIdx.x & 15;
    const uint32_t cntE = cnt[e];
    const int m0 = mt * 128;
    if ((uint32_t)m0 >= cntE) return;
    const int n0 = blockIdx.y * 128;
    const int tid = threadIdx.x;
    __shared__ ushort Asm[128][40];
    __shared__ ushort Bsm[128][40];
    __shared__ uint32_t s_route[128];
    if (tid < 128) {
        const uint32_t idx = (uint32_t)(m0 + tid);
        s_route[tid] = (idx < cntE) ? route[e * T_TOKENS + idx] : 0xFFFFFFFFu;
    }
    __syncthreads();
    const int ar = tid >> 1, ah = tid & 1;
    const uint32_t s_a = s_route[ar];
    size_t arow = 0;
    if (s_a != 0xFFFFFFFFu) arow = FIRST ? (size_t)(s_a >> 1) : (size_t)s_a;
    const ushort* asrc = Abuf + arow * KD + ah * 16;
    const int c4 = tid & 31, kq = tid >> 5;
    const float* wbase = W + (size_t)e * KD * ND + (size_t)n0 + (size_t)c4 * 4;
    f32x4 acc[4][4];
#pragma unroll
    for (int i = 0; i < 4; ++i)
#pragma unroll
        for (int j = 0; j < 4; ++j) acc[i][j] = (f32x4){0.f, 0.f, 0.f, 0.f};
    const int lane = tid & 63, wv = tid >> 6;
    const int wm = wv >> 1, wn = wv & 1;
    const int q = lane & 15, g = lane >> 4;
    for (int k0 = 0; k0 < KD; k0 += 32) {
        {
            const uint4* src = reinterpret_cast<const uint4*>(asrc + k0);
            const uint4 v0 = src[0];
            const uint4 v1 = src[1];
            *reinterpret_cast<uint4*>(&Asm[ar][ah * 16]) = v0;
            *reinterpret_cast<uint4*>(&Asm[ar][ah * 16 + 8]) = v1;
        }
        {
            ushort vals[4][4];
#pragma unroll
            for (int r = 0; r < 4; ++r) {
                const float4 v = *reinterpret_cast<const float4*>(
                    wbase + (size_t)(k0 + kq * 4 + r) * ND);
                vals[r][0] = f2bf(v.x); vals[r][1] = f2bf(v.y);
                vals[r][2] = f2bf(v.z); vals[r][3] = f2bf(v.w);
            }
#pragma unroll
            for (int c = 0; c < 4; ++c) {
                const ushort4 o = { vals[0][c], vals[1][c], vals[2][c], vals[3][c] };
                *reinterpret_cast<ushort4*>(&Bsm[c4 * 4 + c][kq * 4]) = o;
            }
        }
        __syncthreads();
        bf16x8 af[4], bfr[4];
#pragma unroll
        for (int mi = 0; mi < 4; ++mi)
            af[mi] = *reinterpret_cast<const bf16x8*>(&Asm[wm * 64 + mi * 16 + q][g * 8]);
#pragma unroll
        for (int ni = 0; ni < 4; ++ni)
            bfr[ni] = *reinterpret_cast<const bf16x8*>(&Bsm[wn * 64 + ni * 16 + q][g * 8]);
#pragma unroll
        for (int mi = 0; mi < 4; ++mi)
#pragma unroll
            for (int ni = 0; ni < 4; ++ni)
                acc[mi][ni] = __builtin_amdgcn_mfma_f32_16x16x32_bf16(
                    af[mi], bfr[ni], acc[mi][ni], 0, 0, 0);
        __syncthreads();
    }
#pragma unroll
    for (int mi = 0; mi < 4; ++mi) {
#pragma unroll
        for (int ni = 0; ni < 4; ++ni) {
            const int gcol = n0 + wn * 64 + ni * 16 + q;
#pragma unroll
            for (int j = 0; j < 4; ++j) {
                const int row = wm * 64 + mi * 16 + g * 4 + j;
                if ((uint32_t)(m0 + row) < cntE) {
                    const uint32_t s = s_route[row];
                    float v = acc[mi][ni][j] + bias[e * ND + gcol];
                    if (FIRST) {
                        v = fmaxf(v, 0.f);
                        hout[(size_t)s * ND + gcol] = f2bf(v);
                    } else {
                        yout[(size_t)s * ND + gcol] = v * prob[s];
                    }
                }
            }
        }
    }
}

__global__ __launch_bounds__(256) void combine1(const float* __restrict__ yc,
                                                float* __restrict__ out)
{
    const int gid = blockIdx.x * 256 + threadIdx.x;
    const int t = gid >> 8;
    const int dq = gid & 255;
    const float4 va = reinterpret_cast<const float4*>(yc)[(size_t)(2 * t) * 256 + dq];
    const float4 vb = reinterpret_cast<const float4*>(yc)[(size_t)(2 * t + 1) * 256 + dq];
    const float4 o = { va.x + vb.x, va.y + vb.y, va.z + vb.z, va.w + vb.w };
    reinterpret_cast<float4*>(out)[gid] = o;
}

// ---------------- launch ----------------
extern "C" void kernel_launch(void* const* d_in, const int* in_sizes, int n_in,
                              void* d_out, int out_size, void* d_ws, size_t ws_size,
                              hipStream_t stream)
{
    const float* x  = (const float*)d_in[0];
    const float* gw = (const float*)d_in[1];
    const float* gb = (const float*)d_in[2];
    const float* W1 = (const float*)d_in[3];
    const float* b1 = (const float*)d_in[4];
    const float* W2 = (const float*)d_in[5];
    const float* b2 = (const float*)d_in[6];
    float* out = (float*)d_out;
    char* ws = (char*)d_ws;

    // ---- layout (~109 MB; no weight-transpose buffers) ----
    const size_t OFF_XB    = 0;                        // 4 MiB
    const size_t OFF_H     = 4194304;                  // (NSLOTS+128)*4096*2
    const size_t OFF_ROUTE = 38797312;                 // 64 KiB
    const size_t OFF_CNT   = 38862848;                 // 64 B
    const size_t OFF_OFFS  = 38862912;                 // 64 B
    const size_t OFF_PROB  = 38862976;                 // 16 KiB
    const size_t OFF_EPK   = 38879360;                 // 16 KiB
    const size_t OFF_YC    = 41943040;                 // 64 MiB (4 z-splits)
    const size_t NEED      = 109051904ull;

    if (ws_size >= NEED) {
        ushort*   xb    = (ushort*)(ws + OFF_XB);
        ushort*   h     = (ushort*)(ws + OFF_H);
        float*    yc    = (float*)(ws + OFF_YC);
        uint32_t* route = (uint32_t*)(ws + OFF_ROUTE);
        uint32_t* cnt   = (uint32_t*)(ws + OFF_CNT);
        uint32_t* offs  = (uint32_t*)(ws + OFF_OFFS);
        float*    prob  = (float*)(ws + OFF_PROB);
        uint32_t* epk   = (uint32_t*)(ws + OFF_EPK);

        hipLaunchKernelGGL(init_cnt, dim3(1), dim3(64), 0, stream, cnt);
        // fused prep: gate_route (512) | convert_x (2048)
        hipLaunchKernelGGL(prep_kernel, dim3(2560), dim3(256), 0, stream,
                           x, gw, gb, route, cnt, prob, epk, xb);
        hipLaunchKernelGGL(prefix_offs, dim3(1), dim3(64), 0, stream, cnt, offs);
        // GEMM1: 128x128, NMT=16, NT=32 (4096 blocks, XCD-swizzled), fp32 W1
        hipLaunchKernelGGL((moe_gemm12<DM, DF, true, 1, 16, 32>),
                           dim3(NEXP * 16 * 32, 1, 1), dim3(256), 0, stream,
                           xb, W1, b1, route, cnt, offs, prob, h, (float*)nullptr);
        // GEMM2: 128x128, split-K=4, NMT=16, NT=8 (1024x4 blocks), fp32 W2
        hipLaunchKernelGGL((moe_gemm12<DF, DM, false, 4, 16, 8>),
                           dim3(NEXP * 16 * 8, 1, 4), dim3(256), 0, stream,
                           h, W2, (const float*)nullptr, route, cnt, offs,
                           (const float*)nullptr, (ushort*)nullptr, yc);
        hipLaunchKernelGGL(combine5, dim3(T_TOKENS * DM / 1024), dim3(256), 0, stream,
                           yc, epk, offs, prob, b2, out);
    } else {
        // ---- fallback: round-1 layout (~55 MB) ----
        const size_t F_XB = 0, F_H = 4194304, F_YC = 37748736;
        const size_t F_ROUTE = 54525952, F_CNT = 54591488, F_PROB = 54591552;
        ushort*   xb    = (ushort*)(ws + F_XB);
        ushort*   h     = (ushort*)(ws + F_H);
        float*    yc    = (float*)(ws + F_YC);
        uint32_t* route = (uint32_t*)(ws + F_ROUTE);
        uint32_t* cnt   = (uint32_t*)(ws + F_CNT);
        float*    prob  = (float*)(ws + F_PROB);

        hipLaunchKernelGGL(init_cnt, dim3(1), dim3(64), 0, stream, cnt);
        hipLaunchKernelGGL(gate_route_fb, dim3(T_TOKENS / 4), dim3(256), 0, stream,
                           x, gw, gb, route, cnt, prob);
        hipLaunchKernelGGL(convert_x_fb, dim3(T_TOKENS * DM / 1024), dim3(256), 0, stream, x, xb);
        hipLaunchKernelGGL((moe_gemm_v1<DM, DF, true>), dim3(NEXP * 16, DF / 128),
                           dim3(256), 0, stream, xb, W1, b1, route, cnt, prob,
                           h, (float*)nullptr);
        hipLaunchKernelGGL((moe_gemm_v1<DF, DM, false>), dim3(NEXP * 16, DM / 128),
                           dim3(256), 0, stream, h, W2, b2, route, cnt, prob,
                           (ushort*)nullptr, yc);
        hipLaunchKernelGGL(combine1, dim3(T_TOKENS * DM / 1024), dim3(256), 0, stream, yc, out);
    }
}

// Round 14
// 286.915 us; speedup vs baseline: 1.1786x; 1.1786x over previous
//
#include <hip/hip_runtime.h>
#include <stdint.h>

#define T_TOKENS 2048
#define DM 1024
#define DF 4096
#define NEXP 8
#define NSLOTS (T_TOKENS * 2)

typedef __bf16 bf16x8 __attribute__((ext_vector_type(8)));
typedef float f32x4 __attribute__((ext_vector_type(4)));

__device__ __forceinline__ ushort f2bf(float f) {
    union { float f; uint32_t u; } v; v.f = f;
    uint32_t r = v.u + 0x7FFFu + ((v.u >> 16) & 1u);
    return (ushort)(r >> 16);
}

__device__ __forceinline__ void gload16(const ushort* g, ushort* l) {
    __builtin_amdgcn_global_load_lds(
        (const __attribute__((address_space(1))) uint32_t*)g,
        (__attribute__((address_space(3))) uint32_t*)l,
        16, 0, 0);
}

// ---- classic conflict-free 32x32 transpose via [32][33] float LDS tile ----
// bank(T[r][c]) = (33r + c) mod 32 = (r + c) mod 32 -> <=2-way on both phases.
// One call transposes a 32n x 128k strip (4 tiles) of W[e] (K x N, fp32)
// into Wb[e] (N x K, bf16).
template<int K, int N>
__device__ __forceinline__ void transpose_strip(
    const float* __restrict__ W, ushort* __restrict__ Wb,
    float (*T)[33], int e, int k0, int n0, int tid)
{
    const int lrow = tid >> 3;             // 0..31  (k within tile)
    const int lc4  = (tid & 7) * 4;        // 0..28  (n quad)
    const int n    = tid >> 3;             // 0..31  (n for output)
    const int k4   = (tid & 7) * 4;        // 0..28  (k quad for output)
#pragma unroll 1
    for (int kk = 0; kk < 4; ++kk) {
        const int kb = k0 + kk * 32;
        const float4 v = *reinterpret_cast<const float4*>(
            W + ((size_t)e * K + kb + lrow) * N + n0 + lc4);
        T[lrow][lc4 + 0] = v.x;
        T[lrow][lc4 + 1] = v.y;
        T[lrow][lc4 + 2] = v.z;
        T[lrow][lc4 + 3] = v.w;
        __syncthreads();
        const ushort4 o = { f2bf(T[k4 + 0][n]), f2bf(T[k4 + 1][n]),
                            f2bf(T[k4 + 2][n]), f2bf(T[k4 + 3][n]) };
        *reinterpret_cast<ushort4*>(
            Wb + ((size_t)e * N + n0 + n) * K + kb + k4) = o;
        __syncthreads();
    }
}

// ---------------- init: zero expert counters ----------------
__global__ void init_cnt(uint32_t* cnt) {
    if (threadIdx.x < NEXP) cnt[threadIdx.x] = 0;
}

// ---------------- exclusive prefix over the 8 counts ----------------
__global__ void prefix_offs(const uint32_t* __restrict__ cnt,
                            uint32_t* __restrict__ offs)
{
    if (threadIdx.x == 0) {
        uint32_t a = 0;
#pragma unroll
        for (int e = 0; e < NEXP; ++e) { offs[e] = a; a += cnt[e]; }
        offs[NEXP] = a;
    }
}

// == prep: gate_route [0,512) | convert_x [512,2560) | trW1 [2560,10752) ======
__global__ __launch_bounds__(256) void prep_kernel(
    const float* __restrict__ x, const float* __restrict__ gw,
    const float* __restrict__ gb, const float* __restrict__ W1,
    uint32_t* __restrict__ route, uint32_t* __restrict__ cnt,
    float* __restrict__ prob, uint32_t* __restrict__ epk,
    ushort* __restrict__ xb, ushort* __restrict__ w1b)
{
    __shared__ float T[32][33];
    const int bx = blockIdx.x;
    const int tid = threadIdx.x;

    if (bx < 512) {
        // ---- gate + route: one wave per token ----
        const int w = tid >> 6;
        const int lane = tid & 63;
        const int t = bx * 4 + w;
        float acc[NEXP];
#pragma unroll
        for (int e = 0; e < NEXP; ++e) acc[e] = 0.f;
        const float* xr = x + (size_t)t * DM;
#pragma unroll
        for (int j = 0; j < DM / 64; ++j) {
            const int d = j * 64 + lane;
            const float xv = xr[d];
            const float* g = gw + (size_t)d * NEXP;
#pragma unroll
            for (int e = 0; e < NEXP; ++e) acc[e] += xv * g[e];
        }
#pragma unroll
        for (int e = 0; e < NEXP; ++e) {
#pragma unroll
            for (int off = 32; off > 0; off >>= 1)
                acc[e] += __shfl_xor(acc[e], off);
            acc[e] += gb[e];
        }
        if (lane == 0) {
            int e0 = 0; float v0 = acc[0];
#pragma unroll
            for (int e = 1; e < NEXP; ++e) if (acc[e] > v0) { v0 = acc[e]; e0 = e; }
            int e1 = -1; float v1 = -1e30f;
#pragma unroll
            for (int e = 0; e < NEXP; ++e) if (e != e0 && acc[e] > v1) { v1 = acc[e]; e1 = e; }
            const float ex = expf(v1 - v0);
            const float inv = 1.f / (1.f + ex);
            prob[t * 2 + 0] = inv;
            prob[t * 2 + 1] = ex * inv;
            uint32_t pos = atomicAdd(&cnt[e0], 1u);
            route[e0 * T_TOKENS + pos] = (uint32_t)(t * 2);
            epk[t * 2] = ((uint32_t)e0 << 16) | pos;
            pos = atomicAdd(&cnt[e1], 1u);
            route[e1 * T_TOKENS + pos] = (uint32_t)(t * 2 + 1);
            epk[t * 2 + 1] = ((uint32_t)e1 << 16) | pos;
        }
    } else if (bx < 2560) {
        // ---- x fp32 -> bf16 ----
        const int i = ((bx - 512) * 256 + tid) * 4;
        const float4 v = *reinterpret_cast<const float4*>(x + i);
        ushort4 o;
        o.x = f2bf(v.x); o.y = f2bf(v.y); o.z = f2bf(v.z); o.w = f2bf(v.w);
        *reinterpret_cast<ushort4*>(xb + i) = o;
    } else {
        // ---- W1 [E][DM][DF] -> w1b [E][DF][DM] bf16; 32n x 128k strip/block
        const int rel = bx - 2560;        // 0..8191
        const int e   = rel >> 10;        // 1024 blocks/expert
        const int r   = rel & 1023;
        const int ns  = r & 127;          // DF/32 = 128 n-strips
        const int ks  = r >> 7;           // DM/128 = 8 k-strips
        transpose_strip<DM, DF>(W1, w1b, T, e, ks * 128, ns * 32, tid);
    }
}

// ====== fused GEMM1 [0,4096) + transpose W2 [4096,12288) =====================
// GEMM1 branch byte-identical to R10's moe_gemm10 (85us measured): 128x128,
// BK=32 dbuf, chunk-XOR swizzle, counted vmcnt(4), XCD-chunked swizzle.
// trW2 uses the conflict-free [32][33] tile transpose.
__global__ __launch_bounds__(256, 4) void gemm1_trw2(
    const ushort* __restrict__ xb, const ushort* __restrict__ w1b,
    const float* __restrict__ b1, const uint32_t* __restrict__ route,
    const uint32_t* __restrict__ cnt, const uint32_t* __restrict__ offs,
    const float* __restrict__ prob, ushort* __restrict__ hout,
    const float* __restrict__ W2, ushort* __restrict__ w2b)
{
    __shared__ __attribute__((aligned(16))) char smem[33792];
    const int bx0 = blockIdx.x;
    const int tid = threadIdx.x;

    if (bx0 < 4096) {
        // -------- GEMM1 (KD=DM, ND=DF, NMT=16, NT=32) --------
        ushort* Asm = (ushort*)smem;                       // [2][128*32] 16KB
        ushort* Bsm = (ushort*)(smem + 16384);             // [2][128*32] 16KB
        uint32_t* s_route = (uint32_t*)(smem + 32768);     // 512B
        float* s_p = (float*)(smem + 33280);               // 512B

        const int cpx = (NEXP * 16 * 32) >> 3;             // 512
        const int wk  = (bx0 & 7) * cpx + (bx0 >> 3);
        const int e   = wk / (16 * 32);
        const int r   = wk % (16 * 32);
        const int nt  = r / 16;
        const int mt  = r % 16;
        const uint32_t cntE = cnt[e];
        const int m0 = mt * 128;
        if ((uint32_t)m0 >= cntE) return;
        const uint32_t hb = offs[e];
        const int n0 = nt * 128;
        const int niter = DM / 32;

        if (tid < 128) {
            const uint32_t idx = (uint32_t)(m0 + tid);
            const uint32_t s = (idx < cntE) ? route[e * T_TOKENS + idx] : 0u;
            s_route[tid] = s;
            s_p[tid] = prob[s];
        }
        __syncthreads();

        const int w = tid >> 6, l = tid & 63;
        const ushort* asrc[2];
        const ushort* bsrc[2];
#pragma unroll
        for (int i = 0; i < 2; ++i) {
            const int chunk = (w * 2 + i) * 64 + l;
            const int row = chunk >> 2;
            const int c   = chunk & 3;
            const int cs  = c ^ ((row >> 1) & 3);
            const size_t arow = (size_t)(s_route[row] >> 1);
            asrc[i] = xb + arow * DM + cs * 8;
            bsrc[i] = w1b + ((size_t)e * DF + n0 + row) * DM + cs * 8;
        }

        f32x4 acc[4][4];
#pragma unroll
        for (int i = 0; i < 4; ++i)
#pragma unroll
            for (int j = 0; j < 4; ++j) acc[i][j] = (f32x4){0.f, 0.f, 0.f, 0.f};

        const int q = l & 15, g = l >> 4;
        const int wm = w >> 1, wn = w & 1;
        int aoff[4], boff[4];
#pragma unroll
        for (int mi = 0; mi < 4; ++mi) {
            int row = wm * 64 + mi * 16 + q;
            aoff[mi] = row * 64 + (g ^ ((row >> 1) & 3)) * 16;
            row = wn * 64 + mi * 16 + q;
            boff[mi] = row * 64 + (g ^ ((row >> 1) & 3)) * 16;
        }

#pragma unroll
        for (int i = 0; i < 2; ++i) gload16(asrc[i], Asm + (w * 2 + i) * 512);
#pragma unroll
        for (int i = 0; i < 2; ++i) gload16(bsrc[i], Bsm + (w * 2 + i) * 512);

        int cur = 0;
        for (int t = 0; t < niter; ++t) {
            if (t + 1 < niter) {
                ushort* ad = Asm + (cur ^ 1) * (128 * 32) + (w * 2) * 512;
                ushort* bd = Bsm + (cur ^ 1) * (128 * 32) + (w * 2) * 512;
                const int k1 = (t + 1) * 32;
#pragma unroll
                for (int i = 0; i < 2; ++i) gload16(asrc[i] + k1, ad + i * 512);
#pragma unroll
                for (int i = 0; i < 2; ++i) gload16(bsrc[i] + k1, bd + i * 512);
                asm volatile("s_waitcnt vmcnt(4)" ::: "memory");
            } else {
                asm volatile("s_waitcnt vmcnt(0)" ::: "memory");
            }
            __builtin_amdgcn_s_barrier();
            __builtin_amdgcn_sched_barrier(0);

            const char* Ab = (const char*)(Asm + cur * (128 * 32));
            const char* Bb = (const char*)(Bsm + cur * (128 * 32));
            bf16x8 af[4], bv[4];
#pragma unroll
            for (int mi = 0; mi < 4; ++mi)
                af[mi] = *reinterpret_cast<const bf16x8*>(Ab + aoff[mi]);
#pragma unroll
            for (int ni = 0; ni < 4; ++ni)
                bv[ni] = *reinterpret_cast<const bf16x8*>(Bb + boff[ni]);
            __builtin_amdgcn_s_setprio(1);
#pragma unroll
            for (int mi = 0; mi < 4; ++mi)
#pragma unroll
                for (int ni = 0; ni < 4; ++ni)
                    acc[mi][ni] = __builtin_amdgcn_mfma_f32_16x16x32_bf16(
                        af[mi], bv[ni], acc[mi][ni], 0, 0, 0);
            __builtin_amdgcn_s_setprio(0);
            __builtin_amdgcn_s_barrier();
            cur ^= 1;
        }

#pragma unroll
        for (int mi = 0; mi < 4; ++mi) {
#pragma unroll
            for (int ni = 0; ni < 4; ++ni) {
                const int gcol = n0 + wn * 64 + ni * 16 + q;
#pragma unroll
                for (int j = 0; j < 4; ++j) {
                    const int row = wm * 64 + mi * 16 + g * 4 + j;
                    if ((uint32_t)(m0 + row) < cntE) {
                        const size_t grow = (size_t)(hb + m0 + row);
                        float v = acc[mi][ni][j] + b1[e * DF + gcol];
                        v = fmaxf(v, 0.f) * s_p[row];
                        hout[grow * DF + gcol] = f2bf(v);
                    }
                }
            }
        }
    } else {
        // ---- W2 [E][DF][DM] -> w2b [E][DM][DF] bf16; 32n x 128k strip/block
        float (*T)[33] = reinterpret_cast<float(*)[33]>(smem);
        const int rel = bx0 - 4096;       // 0..8191
        const int e   = rel >> 10;        // 1024 blocks/expert
        const int r   = rel & 1023;
        const int ns  = r & 31;           // DM/32 = 32 n-strips
        const int ks  = r >> 5;           // DF/128 = 32 k-strips
        transpose_strip<DF, DM>(W2, w2b, T, e, ks * 128, ns * 32, tid);
    }
}

// -------- grouped expert GEMM (R10 structure, used for GEMM2) ----------------
template<int KD, int ND, bool FIRST, int SPLIT, int NMT, int NT>
__global__ __launch_bounds__(256, 4) void moe_gemm10(
    const ushort* __restrict__ Abuf,
    const ushort* __restrict__ Wb,
    const float* __restrict__ bias,
    const uint32_t* __restrict__ route,
    const uint32_t* __restrict__ cnt,
    const uint32_t* __restrict__ offs,
    const float* __restrict__ prob,
    ushort* __restrict__ hout,
    float* __restrict__ yout)
{
    const int bx0 = blockIdx.x;
    const int cpx = (NEXP * NMT * NT) >> 3;
    const int wk  = (bx0 & 7) * cpx + (bx0 >> 3);
    const int e   = wk / (NMT * NT);
    const int r   = wk % (NMT * NT);
    const int nt  = r / NMT;
    const int mt  = r % NMT;
    const uint32_t cntE = cnt[e];
    const int m0 = mt * 128;
    if ((uint32_t)m0 >= cntE) return;
    const uint32_t hb = offs[e];
    const int n0 = nt * 128;
    const int z  = (SPLIT > 1) ? (int)blockIdx.z : 0;
    const int kbeg = z * (KD / SPLIT);
    const int niter = (KD / SPLIT) / 32;

    __shared__ ushort As[2][128 * 32];
    __shared__ ushort Bs[2][128 * 32];
    __shared__ uint32_t s_route[128];
    __shared__ float s_p[128];

    const int tid = threadIdx.x;
    if (FIRST) {
        if (tid < 128) {
            const uint32_t idx = (uint32_t)(m0 + tid);
            const uint32_t s = (idx < cntE) ? route[e * T_TOKENS + idx] : 0u;
            s_route[tid] = s;
            s_p[tid] = prob[s];
        }
        __syncthreads();
    }

    const int w = tid >> 6, l = tid & 63;
    const ushort* asrc[2];
    const ushort* bsrc[2];
#pragma unroll
    for (int i = 0; i < 2; ++i) {
        const int chunk = (w * 2 + i) * 64 + l;
        const int row = chunk >> 2;
        const int c   = chunk & 3;
        const int cs  = c ^ ((row >> 1) & 3);
        size_t arow;
        if (FIRST) arow = (size_t)(s_route[row] >> 1);
        else       arow = (size_t)(hb + m0 + row);
        asrc[i] = Abuf + arow * KD + cs * 8 + kbeg;
        bsrc[i] = Wb + ((size_t)e * ND + n0 + row) * KD + cs * 8 + kbeg;
    }

    f32x4 acc[4][4];
#pragma unroll
    for (int i = 0; i < 4; ++i)
#pragma unroll
        for (int j = 0; j < 4; ++j) acc[i][j] = (f32x4){0.f, 0.f, 0.f, 0.f};

    const int q = l & 15, g = l >> 4;
    const int wm = w >> 1, wn = w & 1;
    int aoff[4], boff[4];
#pragma unroll
    for (int mi = 0; mi < 4; ++mi) {
        int row = wm * 64 + mi * 16 + q;
        aoff[mi] = row * 64 + (g ^ ((row >> 1) & 3)) * 16;
        row = wn * 64 + mi * 16 + q;
        boff[mi] = row * 64 + (g ^ ((row >> 1) & 3)) * 16;
    }

    ushort* const abase0 = &As[0][0];
    ushort* const bbase0 = &Bs[0][0];

#pragma unroll
    for (int i = 0; i < 2; ++i) gload16(asrc[i], abase0 + (w * 2 + i) * 512);
#pragma unroll
    for (int i = 0; i < 2; ++i) gload16(bsrc[i], bbase0 + (w * 2 + i) * 512);

    int cur = 0;
    for (int t = 0; t < niter; ++t) {
        if (t + 1 < niter) {
            ushort* ad = abase0 + (cur ^ 1) * (128 * 32) + (w * 2) * 512;
            ushort* bd = bbase0 + (cur ^ 1) * (128 * 32) + (w * 2) * 512;
            const int k1 = (t + 1) * 32;
#pragma unroll
            for (int i = 0; i < 2; ++i) gload16(asrc[i] + k1, ad + i * 512);
#pragma unroll
            for (int i = 0; i < 2; ++i) gload16(bsrc[i] + k1, bd + i * 512);
            asm volatile("s_waitcnt vmcnt(4)" ::: "memory");
        } else {
            asm volatile("s_waitcnt vmcnt(0)" ::: "memory");
        }
        __builtin_amdgcn_s_barrier();
        __builtin_amdgcn_sched_barrier(0);

        const char* Ab = (const char*)(abase0 + cur * (128 * 32));
        const char* Bb = (const char*)(bbase0 + cur * (128 * 32));
        bf16x8 af[4], bv[4];
#pragma unroll
        for (int mi = 0; mi < 4; ++mi)
            af[mi] = *reinterpret_cast<const bf16x8*>(Ab + aoff[mi]);
#pragma unroll
        for (int ni = 0; ni < 4; ++ni)
            bv[ni] = *reinterpret_cast<const bf16x8*>(Bb + boff[ni]);
        __builtin_amdgcn_s_setprio(1);
#pragma unroll
        for (int mi = 0; mi < 4; ++mi)
#pragma unroll
            for (int ni = 0; ni < 4; ++ni)
                acc[mi][ni] = __builtin_amdgcn_mfma_f32_16x16x32_bf16(
                    af[mi], bv[ni], acc[mi][ni], 0, 0, 0);
        __builtin_amdgcn_s_setprio(0);
        __builtin_amdgcn_s_barrier();
        cur ^= 1;
    }

#pragma unroll
    for (int mi = 0; mi < 4; ++mi) {
#pragma unroll
        for (int ni = 0; ni < 4; ++ni) {
            const int gcol = n0 + wn * 64 + ni * 16 + q;
#pragma unroll
            for (int j = 0; j < 4; ++j) {
                const int row = wm * 64 + mi * 16 + g * 4 + j;
                if ((uint32_t)(m0 + row) < cntE) {
                    const size_t grow = (size_t)(hb + m0 + row);
                    if (FIRST) {
                        float v = acc[mi][ni][j] + bias[e * ND + gcol];
                        v = fmaxf(v, 0.f) * s_p[row];
                        hout[grow * ND + gcol] = f2bf(v);
                    } else {
                        yout[((size_t)z * NSLOTS + grow) * ND + gcol] = acc[mi][ni][j];
                    }
                }
            }
        }
    }
}

// ------- combine: out[t] = p0*b2[e0] + p1*b2[e1] + sum_z (yc[z][r0]+yc[z][r1])
__global__ __launch_bounds__(256) void combine5(
    const float* __restrict__ yc, const uint32_t* __restrict__ epk,
    const uint32_t* __restrict__ offs, const float* __restrict__ prob,
    const float* __restrict__ b2, float* __restrict__ out)
{
    const int gid = blockIdx.x * 256 + threadIdx.x;
    const int t = gid >> 8;
    const int dq = gid & 255;
    const uint32_t p0 = epk[2 * t], p1 = epk[2 * t + 1];
    const uint32_t e0 = p0 >> 16, e1 = p1 >> 16;
    const uint32_t r0 = offs[e0] + (p0 & 0xFFFFu);
    const uint32_t r1 = offs[e1] + (p1 & 0xFFFFu);
    const float w0 = prob[2 * t], w1 = prob[2 * t + 1];
    const float4 bb0 = reinterpret_cast<const float4*>(b2 + (size_t)e0 * DM)[dq];
    const float4 bb1 = reinterpret_cast<const float4*>(b2 + (size_t)e1 * DM)[dq];
    float4 o = { w0 * bb0.x + w1 * bb1.x, w0 * bb0.y + w1 * bb1.y,
                 w0 * bb0.z + w1 * bb1.z, w0 * bb0.w + w1 * bb1.w };
    const float4* Y = reinterpret_cast<const float4*>(yc);
#pragma unroll
    for (int zz = 0; zz < 4; ++zz) {
        const float4 a = Y[((size_t)zz * NSLOTS + r0) * 256 + dq];
        const float4 b = Y[((size_t)zz * NSLOTS + r1) * 256 + dq];
        o.x += a.x + b.x; o.y += a.y + b.y; o.z += a.z + b.z; o.w += a.w + b.w;
    }
    reinterpret_cast<float4*>(out)[gid] = o;
}

// ================= fallback path (round-1, works in ~55 MB ws) =================
__global__ __launch_bounds__(256) void gate_route_fb(
    const float* __restrict__ x, const float* __restrict__ gw,
    const float* __restrict__ gb,
    uint32_t* __restrict__ route, uint32_t* __restrict__ cnt,
    float* __restrict__ prob)
{
    const int w = threadIdx.x >> 6;
    const int lane = threadIdx.x & 63;
    const int t = blockIdx.x * 4 + w;
    float acc[NEXP];
#pragma unroll
    for (int e = 0; e < NEXP; ++e) acc[e] = 0.f;
    const float* xr = x + (size_t)t * DM;
#pragma unroll
    for (int j = 0; j < DM / 64; ++j) {
        const int d = j * 64 + lane;
        const float xv = xr[d];
        const float* g = gw + (size_t)d * NEXP;
#pragma unroll
        for (int e = 0; e < NEXP; ++e) acc[e] += xv * g[e];
    }
#pragma unroll
    for (int e = 0; e < NEXP; ++e) {
#pragma unroll
        for (int off = 32; off > 0; off >>= 1)
            acc[e] += __shfl_xor(acc[e], off);
        acc[e] += gb[e];
    }
    if (lane == 0) {
        int e0 = 0; float v0 = acc[0];
#pragma unroll
        for (int e = 1; e < NEXP; ++e) if (acc[e] > v0) { v0 = acc[e]; e0 = e; }
        int e1 = -1; float v1 = -1e30f;
#pragma unroll
        for (int e = 0; e < NEXP; ++e) if (e != e0 && acc[e] > v1) { v1 = acc[e]; e1 = e; }
        const float ex = expf(v1 - v0);
        const float inv = 1.f / (1.f + ex);
        prob[t * 2 + 0] = inv;
        prob[t * 2 + 1] = ex * inv;
        uint32_t pos = atomicAdd(&cnt[e0], 1u);
        route[e0 * T_TOKENS + pos] = (uint32_t)(t * 2);
        pos = atomicAdd(&cnt[e1], 1u);
        route[e1 * T_TOKENS + pos] = (uint32_t)(t * 2 + 1);
    }
}

__global__ __launch_bounds__(256) void convert_x_fb(const float* __restrict__ x,
                                                    ushort* __restrict__ xb)
{
    const int i = (blockIdx.x * 256 + threadIdx.x) * 4;
    const float4 v = *reinterpret_cast<const float4*>(x + i);
    ushort4 o;
    o.x = f2bf(v.x); o.y = f2bf(v.y); o.z = f2bf(v.z); o.w = f2bf(v.w);
    *reinterpret_cast<ushort4*>(xb + i) = o;
}

template<int KD, int ND, bool FIRST>
__global__ __launch_bounds__(256) void moe_gemm_v1(
    const ushort* __restrict__ Abuf, const float* __restrict__ W,
    const float* __restrict__ bias, const uint32_t* __restrict__ route,
    const uint32_t* __restrict__ cnt, const float* __restrict__ prob,
    ushort* __restrict__ hout, float* __restrict__ yout)
{
    const int e = blockIdx.x >> 4;
    const int mt = blockIdx.x & 15;
    const uint32_t cntE = cnt[e];
    const int m0 = mt * 128;
    if ((uint32_t)m0 >= cntE) return;
    const int n0 = blockIdx.y * 128;
    const int tid = threadIdx.x;
    __shared__ ushort Asm[128][40];
    __shared__ ushort Bsm[128][40];
    __shared__ uint32_t s_route[128];
    if (tid < 128) {
        const uint32_t idx = (uint32_t)(m0 + tid);
        s_route[tid] = (idx < cntE) ? route[e * T_TOKENS + idx] : 0xFFFFFFFFu;
    }
    __syncthreads();
    const int ar = tid >> 1, ah = tid & 1;
    const uint32_t s_a = s_route[ar];
    size_t arow = 0;
    if (s_a != 0xFFFFFFFFu) arow = FIRST ? (size_t)(s_a >> 1) : (size_t)s_a;
    const ushort* asrc = Abuf + arow * KD + ah * 16;
    const int c4 = tid & 31, kq = tid >> 5;
    const float* wbase = W + (size_t)e * KD * ND + (size_t)n0 + (size_t)c4 * 4;
    f32x4 acc[4][4];
#pragma unroll
    for (int i = 0; i < 4; ++i)
#pragma unroll
        for (int j = 0; j < 4; ++j) acc[i][j] = (f32x4){0.f, 0.f, 0.f, 0.f};
    const int lane = tid & 63, wv = tid >> 6;
    const int wm = wv >> 1, wn = wv & 1;
    const int q = lane & 15, g = lane >> 4;
    for (int k0 = 0; k0 < KD; k0 += 32) {
        {
            const uint4* src = reinterpret_cast<const uint4*>(asrc + k0);
            const uint4 v0 = src[0];
            const uint4 v1 = src[1];
            *reinterpret_cast<uint4*>(&Asm[ar][ah * 16]) = v0;
            *reinterpret_cast<uint4*>(&Asm[ar][ah * 16 + 8]) = v1;
        }
        {
            ushort vals[4][4];
#pragma unroll
            for (int r = 0; r < 4; ++r) {
                const float4 v = *reinterpret_cast<const float4*>(
                    wbase + (size_t)(k0 + kq * 4 + r) * ND);
                vals[r][0] = f2bf(v.x); vals[r][1] = f2bf(v.y);
                vals[r][2] = f2bf(v.z); vals[r][3] = f2bf(v.w);
            }
#pragma unroll
            for (int c = 0; c < 4; ++c) {
                const ushort4 o = { vals[0][c], vals[1][c], vals[2][c], vals[3][c] };
                *reinterpret_cast<ushort4*>(&Bsm[c4 * 4 + c][kq * 4]) = o;
            }
        }
        __syncthreads();
        bf16x8 af[4], bfr[4];
#pragma unroll
        for (int mi = 0; mi < 4; ++mi)
            af[mi] = *reinterpret_cast<const bf16x8*>(&Asm[wm * 64 + mi * 16 + q][g * 8]);
#pragma unroll
        for (int ni = 0; ni < 4; ++ni)
            bfr[ni] = *reinterpret_cast<const bf16x8*>(&Bsm[wn * 64 + ni * 16 + q][g * 8]);
#pragma unroll
        for (int mi = 0; mi < 4; ++mi)
#pragma unroll
            for (int ni = 0; ni < 4; ++ni)
                acc[mi][ni] = __builtin_amdgcn_mfma_f32_16x16x32_bf16(
                    af[mi], bfr[ni], acc[mi][ni], 0, 0, 0);
        __syncthreads();
    }
#pragma unroll
    for (int mi = 0; mi < 4; ++mi) {
#pragma unroll
        for (int ni = 0; ni < 4; ++ni) {
            const int gcol = n0 + wn * 64 + ni * 16 + q;
#pragma unroll
            for (int j = 0; j < 4; ++j) {
                const int row = wm * 64 + mi * 16 + g * 4 + j;
                if ((uint32_t)(m0 + row) < cntE) {
                    const uint32_t s = s_route[row];
                    float v = acc[mi][ni][j] + bias[e * ND + gcol];
                    if (FIRST) {
                        v = fmaxf(v, 0.f);
                        hout[(size_t)s * ND + gcol] = f2bf(v);
                    } else {
                        yout[(size_t)s * ND + gcol] = v * prob[s];
                    }
                }
            }
        }
    }
}

__global__ __launch_bounds__(256) void combine1(const float* __restrict__ yc,
                                                float* __restrict__ out)
{
    const int gid = blockIdx.x * 256 + threadIdx.x;
    const int t = gid >> 8;
    const int dq = gid & 255;
    const float4 va = reinterpret_cast<const float4*>(yc)[(size_t)(2 * t) * 256 + dq];
    const float4 vb = reinterpret_cast<const float4*>(yc)[(size_t)(2 * t + 1) * 256 + dq];
    const float4 o = { va.x + vb.x, va.y + vb.y, va.z + vb.z, va.w + vb.w };
    reinterpret_cast<float4*>(out)[gid] = o;
}

// ---------------- launch ----------------
extern "C" void kernel_launch(void* const* d_in, const int* in_sizes, int n_in,
                              void* d_out, int out_size, void* d_ws, size_t ws_size,
                              hipStream_t stream)
{
    const float* x  = (const float*)d_in[0];
    const float* gw = (const float*)d_in[1];
    const float* gb = (const float*)d_in[2];
    const float* W1 = (const float*)d_in[3];
    const float* b1 = (const float*)d_in[4];
    const float* W2 = (const float*)d_in[5];
    const float* b2 = (const float*)d_in[6];
    float* out = (float*)d_out;
    char* ws = (char*)d_ws;

    // ---- big layout (~168 MB; yc aliases w1b which is dead after GEMM1) ----
    const size_t OFF_XB    = 0;                        // 4 MiB
    const size_t OFF_H     = 4194304;                  // (NSLOTS+128)*4096*2
    const size_t OFF_ROUTE = 38797312;                 // 64 KiB
    const size_t OFF_CNT   = 38862848;                 // 64 B
    const size_t OFF_OFFS  = 38862912;                 // 64 B
    const size_t OFF_PROB  = 38862976;                 // 16 KiB
    const size_t OFF_EPK   = 38879360;                 // 16 KiB
    const size_t OFF_W1B   = 41943040;                 // 64 MiB (aliased by yc)
    const size_t OFF_W2B   = 109051904;                // 64 MiB
    const size_t OFF_YC    = OFF_W1B;                  // 64 MiB (4 z-splits)
    const size_t NEED      = 176160768ull;

    if (ws_size >= NEED) {
        ushort*   xb    = (ushort*)(ws + OFF_XB);
        ushort*   h     = (ushort*)(ws + OFF_H);
        float*    yc    = (float*)(ws + OFF_YC);
        uint32_t* route = (uint32_t*)(ws + OFF_ROUTE);
        uint32_t* cnt   = (uint32_t*)(ws + OFF_CNT);
        uint32_t* offs  = (uint32_t*)(ws + OFF_OFFS);
        float*    prob  = (float*)(ws + OFF_PROB);
        uint32_t* epk   = (uint32_t*)(ws + OFF_EPK);
        ushort*   w1b   = (ushort*)(ws + OFF_W1B);
        ushort*   w2b   = (ushort*)(ws + OFF_W2B);

        hipLaunchKernelGGL(init_cnt, dim3(1), dim3(64), 0, stream, cnt);
        // fused prep: gate_route (512) | convert_x (2048) | trW1 (8192)
        hipLaunchKernelGGL(prep_kernel, dim3(512 + 2048 + 8192), dim3(256), 0, stream,
                           x, gw, gb, W1, route, cnt, prob, epk, xb, w1b);
        hipLaunchKernelGGL(prefix_offs, dim3(1), dim3(64), 0, stream, cnt, offs);
        // fused: GEMM1 (4096, XCD-swizzled) | trW2 (8192)
        hipLaunchKernelGGL(gemm1_trw2, dim3(4096 + 8192), dim3(256), 0, stream,
                           xb, w1b, b1, route, cnt, offs, prob, h, W2, w2b);
        // GEMM2: 128x128, split-K=4, NMT=16, NT=8; yc aliases w1b (dead now)
        hipLaunchKernelGGL((moe_gemm10<DF, DM, false, 4, 16, 8>),
                           dim3(NEXP * 16 * 8, 1, 4), dim3(256), 0, stream,
                           h, w2b, (const float*)nullptr, route, cnt, offs,
                           (const float*)nullptr, (ushort*)nullptr, yc);
        hipLaunchKernelGGL(combine5, dim3(T_TOKENS * DM / 1024), dim3(256), 0, stream,
                           yc, epk, offs, prob, b2, out);
    } else {
        // ---- fallback: round-1 layout (~55 MB) ----
        const size_t F_XB = 0, F_H = 4194304, F_YC = 37748736;
        const size_t F_ROUTE = 54525952, F_CNT = 54591488, F_PROB = 54591552;
        ushort*   xb    = (ushort*)(ws + F_XB);
        ushort*   h     = (ushort*)(ws + F_H);
        float*    yc    = (float*)(ws + F_YC);
        uint32_t* route = (uint32_t*)(ws + F_ROUTE);
        uint32_t* cnt   = (uint32_t*)(ws + F_CNT);
        float*    prob  = (float*)(ws + F_PROB);

        hipLaunchKernelGGL(init_cnt, dim3(1), dim3(64), 0, stream, cnt);
        hipLaunchKernelGGL(gate_route_fb, dim3(T_TOKENS / 4), dim3(256), 0, stream,
                           x, gw, gb, route, cnt, prob);
        hipLaunchKernelGGL(convert_x_fb, dim3(T_TOKENS * DM / 1024), dim3(256), 0, stream, x, xb);
        hipLaunchKernelGGL((moe_gemm_v1<DM, DF, true>), dim3(NEXP * 16, DF / 128),
                           dim3(256), 0, stream, xb, W1, b1, route, cnt, prob,
                           h, (float*)nullptr);
        hipLaunchKernelGGL((moe_gemm_v1<DF, DM, false>), dim3(NEXP * 16, DM / 128),
                           dim3(256), 0, stream, h, W2, b2, route, cnt, prob,
                           (ushort*)nullptr, yc);
        hipLaunchKernelGGL(combine1, dim3(T_TOKENS * DM / 1024), dim3(256), 0, stream, yc, out);
    }
}

// Round 15
// 275.541 us; speedup vs baseline: 1.2272x; 1.0413x over previous
//
#include <hip/hip_runtime.h>
#include <stdint.h>

#define T_TOKENS 2048
#define DM 1024
#define DF 4096
#define NEXP 8
#define NSLOTS (T_TOKENS * 2)

typedef __bf16 bf16x8 __attribute__((ext_vector_type(8)));
typedef float f32x4 __attribute__((ext_vector_type(4)));

__device__ __forceinline__ ushort f2bf(float f) {
    union { float f; uint32_t u; } v; v.f = f;
    uint32_t r = v.u + 0x7FFFu + ((v.u >> 16) & 1u);
    return (ushort)(r >> 16);
}

__device__ __forceinline__ void gload16(const ushort* g, ushort* l) {
    __builtin_amdgcn_global_load_lds(
        (const __attribute__((address_space(1))) uint32_t*)g,
        (__attribute__((address_space(3))) uint32_t*)l,
        16, 0, 0);
}

// ---- transpose v2: 128k x 64n strip per block, 8x [32][33] fp32 micro-tiles.
// Global reads 256B/row (8 float4/thread in flight), ONE barrier, global
// writes 256B/row (ushort8). Phase-1 LDS writes 2-way (free); phase-2 scalar
// reads ~4-way (LDS is not the constraint here).
template<int K, int N>
__device__ __forceinline__ void transpose_strip128(
    const float* __restrict__ W, ushort* __restrict__ Wb,
    float (*T)[32][33], int e, int k0, int n0, int tid)
{
    float4 v[8];
#pragma unroll
    for (int p = 0; p < 8; ++p) {
        const int k = p * 16 + (tid >> 4);
        const int n4 = (tid & 15) * 4;
        v[p] = *reinterpret_cast<const float4*>(
            W + ((size_t)e * K + k0 + k) * N + n0 + n4);
    }
#pragma unroll
    for (int p = 0; p < 8; ++p) {
        const int k = p * 16 + (tid >> 4);
        const int n4 = (tid & 15) * 4;
        const int mt = ((k >> 5) << 1) | (n4 >> 5);
        float* dst = &T[mt][k & 31][n4 & 31];
        dst[0] = v[p].x; dst[1] = v[p].y; dst[2] = v[p].z; dst[3] = v[p].w;
    }
    __syncthreads();
#pragma unroll
    for (int p = 0; p < 4; ++p) {
        const int u = p * 256 + tid;
        const int n = u >> 4;              // 0..63
        const int k8 = (u & 15) * 8;       // 0..120
        union { ushort us[8]; uint4 v4; } o;
#pragma unroll
        for (int i = 0; i < 8; ++i) {
            const int k = k8 + i;
            const int mt = ((k >> 5) << 1) | (n >> 5);
            o.us[i] = f2bf(T[mt][k & 31][n & 31]);
        }
        *reinterpret_cast<uint4*>(
            Wb + ((size_t)e * N + n0 + n) * K + k0 + k8) = o.v4;
    }
}

// ---------------- init: zero expert counters ----------------
__global__ void init_cnt(uint32_t* cnt) {
    if (threadIdx.x < NEXP) cnt[threadIdx.x] = 0;
}

// ---------------- exclusive prefix over the 8 counts ----------------
__global__ void prefix_offs(const uint32_t* __restrict__ cnt,
                            uint32_t* __restrict__ offs)
{
    if (threadIdx.x == 0) {
        uint32_t a = 0;
#pragma unroll
        for (int e = 0; e < NEXP; ++e) { offs[e] = a; a += cnt[e]; }
        offs[NEXP] = a;
    }
}

// == prep: gate_route [0,512) | convert_x [512,2560) | trW1 [2560,6656) =======
__global__ __launch_bounds__(256) void prep_kernel(
    const float* __restrict__ x, const float* __restrict__ gw,
    const float* __restrict__ gb, const float* __restrict__ W1,
    uint32_t* __restrict__ route, uint32_t* __restrict__ cnt,
    float* __restrict__ prob, uint32_t* __restrict__ epk,
    ushort* __restrict__ xb, ushort* __restrict__ w1b)
{
    __shared__ float T[8][32][33];
    const int bx = blockIdx.x;
    const int tid = threadIdx.x;

    if (bx < 512) {
        // ---- gate + route: one wave per token ----
        const int w = tid >> 6;
        const int lane = tid & 63;
        const int t = bx * 4 + w;
        float acc[NEXP];
#pragma unroll
        for (int e = 0; e < NEXP; ++e) acc[e] = 0.f;
        const float* xr = x + (size_t)t * DM;
#pragma unroll
        for (int j = 0; j < DM / 64; ++j) {
            const int d = j * 64 + lane;
            const float xv = xr[d];
            const float* g = gw + (size_t)d * NEXP;
#pragma unroll
            for (int e = 0; e < NEXP; ++e) acc[e] += xv * g[e];
        }
#pragma unroll
        for (int e = 0; e < NEXP; ++e) {
#pragma unroll
            for (int off = 32; off > 0; off >>= 1)
                acc[e] += __shfl_xor(acc[e], off);
            acc[e] += gb[e];
        }
        if (lane == 0) {
            int e0 = 0; float v0 = acc[0];
#pragma unroll
            for (int e = 1; e < NEXP; ++e) if (acc[e] > v0) { v0 = acc[e]; e0 = e; }
            int e1 = -1; float v1 = -1e30f;
#pragma unroll
            for (int e = 0; e < NEXP; ++e) if (e != e0 && acc[e] > v1) { v1 = acc[e]; e1 = e; }
            const float ex = expf(v1 - v0);
            const float inv = 1.f / (1.f + ex);
            prob[t * 2 + 0] = inv;
            prob[t * 2 + 1] = ex * inv;
            uint32_t pos = atomicAdd(&cnt[e0], 1u);
            route[e0 * T_TOKENS + pos] = (uint32_t)(t * 2);
            epk[t * 2] = ((uint32_t)e0 << 16) | pos;
            pos = atomicAdd(&cnt[e1], 1u);
            route[e1 * T_TOKENS + pos] = (uint32_t)(t * 2 + 1);
            epk[t * 2 + 1] = ((uint32_t)e1 << 16) | pos;
        }
    } else if (bx < 2560) {
        // ---- x fp32 -> bf16 ----
        const int i = ((bx - 512) * 256 + tid) * 4;
        const float4 v = *reinterpret_cast<const float4*>(x + i);
        ushort4 o;
        o.x = f2bf(v.x); o.y = f2bf(v.y); o.z = f2bf(v.z); o.w = f2bf(v.w);
        *reinterpret_cast<ushort4*>(xb + i) = o;
    } else {
        // ---- W1 [E][DM][DF] -> w1b [E][DF][DM] bf16; 128k x 64n strip/block
        const int rel = bx - 2560;        // 0..4095
        const int e   = rel >> 9;         // 512 blocks/expert
        const int r   = rel & 511;
        const int ks  = r >> 6;           // DM/128 = 8 k-strips
        const int ns  = r & 63;           // DF/64 = 64 n-strips
        transpose_strip128<DM, DF>(W1, w1b, T, e, ks * 128, ns * 64, tid);
    }
}

// ====== fused GEMM1 [0,4096) + transpose W2 [4096,8192) ======================
// GEMM1 branch byte-identical to R10's moe_gemm10 (85us measured): 128x128,
// BK=32 dbuf, chunk-XOR swizzle, counted vmcnt(4), XCD-chunked swizzle.
// trW2 uses transpose v2 (128k x 64n strips).
__global__ __launch_bounds__(256, 4) void gemm1_trw2(
    const ushort* __restrict__ xb, const ushort* __restrict__ w1b,
    const float* __restrict__ b1, const uint32_t* __restrict__ route,
    const uint32_t* __restrict__ cnt, const uint32_t* __restrict__ offs,
    const float* __restrict__ prob, ushort* __restrict__ hout,
    const float* __restrict__ W2, ushort* __restrict__ w2b)
{
    __shared__ __attribute__((aligned(16))) char smem[33792];
    const int bx0 = blockIdx.x;
    const int tid = threadIdx.x;

    if (bx0 < 4096) {
        // -------- GEMM1 (KD=DM, ND=DF, NMT=16, NT=32) --------
        ushort* Asm = (ushort*)smem;                       // [2][128*32] 16KB
        ushort* Bsm = (ushort*)(smem + 16384);             // [2][128*32] 16KB
        uint32_t* s_route = (uint32_t*)(smem + 32768);     // 512B
        float* s_p = (float*)(smem + 33280);               // 512B

        const int cpx = (NEXP * 16 * 32) >> 3;             // 512
        const int wk  = (bx0 & 7) * cpx + (bx0 >> 3);
        const int e   = wk / (16 * 32);
        const int r   = wk % (16 * 32);
        const int nt  = r / 16;
        const int mt  = r % 16;
        const uint32_t cntE = cnt[e];
        const int m0 = mt * 128;
        if ((uint32_t)m0 >= cntE) return;
        const uint32_t hb = offs[e];
        const int n0 = nt * 128;
        const int niter = DM / 32;

        if (tid < 128) {
            const uint32_t idx = (uint32_t)(m0 + tid);
            const uint32_t s = (idx < cntE) ? route[e * T_TOKENS + idx] : 0u;
            s_route[tid] = s;
            s_p[tid] = prob[s];
        }
        __syncthreads();

        const int w = tid >> 6, l = tid & 63;
        const ushort* asrc[2];
        const ushort* bsrc[2];
#pragma unroll
        for (int i = 0; i < 2; ++i) {
            const int chunk = (w * 2 + i) * 64 + l;
            const int row = chunk >> 2;
            const int c   = chunk & 3;
            const int cs  = c ^ ((row >> 1) & 3);
            const size_t arow = (size_t)(s_route[row] >> 1);
            asrc[i] = xb + arow * DM + cs * 8;
            bsrc[i] = w1b + ((size_t)e * DF + n0 + row) * DM + cs * 8;
        }

        f32x4 acc[4][4];
#pragma unroll
        for (int i = 0; i < 4; ++i)
#pragma unroll
            for (int j = 0; j < 4; ++j) acc[i][j] = (f32x4){0.f, 0.f, 0.f, 0.f};

        const int q = l & 15, g = l >> 4;
        const int wm = w >> 1, wn = w & 1;
        int aoff[4], boff[4];
#pragma unroll
        for (int mi = 0; mi < 4; ++mi) {
            int row = wm * 64 + mi * 16 + q;
            aoff[mi] = row * 64 + (g ^ ((row >> 1) & 3)) * 16;
            row = wn * 64 + mi * 16 + q;
            boff[mi] = row * 64 + (g ^ ((row >> 1) & 3)) * 16;
        }

#pragma unroll
        for (int i = 0; i < 2; ++i) gload16(asrc[i], Asm + (w * 2 + i) * 512);
#pragma unroll
        for (int i = 0; i < 2; ++i) gload16(bsrc[i], Bsm + (w * 2 + i) * 512);

        int cur = 0;
        for (int t = 0; t < niter; ++t) {
            if (t + 1 < niter) {
                ushort* ad = Asm + (cur ^ 1) * (128 * 32) + (w * 2) * 512;
                ushort* bd = Bsm + (cur ^ 1) * (128 * 32) + (w * 2) * 512;
                const int k1 = (t + 1) * 32;
#pragma unroll
                for (int i = 0; i < 2; ++i) gload16(asrc[i] + k1, ad + i * 512);
#pragma unroll
                for (int i = 0; i < 2; ++i) gload16(bsrc[i] + k1, bd + i * 512);
                asm volatile("s_waitcnt vmcnt(4)" ::: "memory");
            } else {
                asm volatile("s_waitcnt vmcnt(0)" ::: "memory");
            }
            __builtin_amdgcn_s_barrier();
            __builtin_amdgcn_sched_barrier(0);

            const char* Ab = (const char*)(Asm + cur * (128 * 32));
            const char* Bb = (const char*)(Bsm + cur * (128 * 32));
            bf16x8 af[4], bv[4];
#pragma unroll
            for (int mi = 0; mi < 4; ++mi)
                af[mi] = *reinterpret_cast<const bf16x8*>(Ab + aoff[mi]);
#pragma unroll
            for (int ni = 0; ni < 4; ++ni)
                bv[ni] = *reinterpret_cast<const bf16x8*>(Bb + boff[ni]);
            __builtin_amdgcn_s_setprio(1);
#pragma unroll
            for (int mi = 0; mi < 4; ++mi)
#pragma unroll
                for (int ni = 0; ni < 4; ++ni)
                    acc[mi][ni] = __builtin_amdgcn_mfma_f32_16x16x32_bf16(
                        af[mi], bv[ni], acc[mi][ni], 0, 0, 0);
            __builtin_amdgcn_s_setprio(0);
            __builtin_amdgcn_s_barrier();
            cur ^= 1;
        }

#pragma unroll
        for (int mi = 0; mi < 4; ++mi) {
#pragma unroll
            for (int ni = 0; ni < 4; ++ni) {
                const int gcol = n0 + wn * 64 + ni * 16 + q;
#pragma unroll
                for (int j = 0; j < 4; ++j) {
                    const int row = wm * 64 + mi * 16 + g * 4 + j;
                    if ((uint32_t)(m0 + row) < cntE) {
                        const size_t grow = (size_t)(hb + m0 + row);
                        float v = acc[mi][ni][j] + b1[e * DF + gcol];
                        v = fmaxf(v, 0.f) * s_p[row];
                        hout[grow * DF + gcol] = f2bf(v);
                    }
                }
            }
        }
    } else {
        // ---- W2 [E][DF][DM] -> w2b [E][DM][DF] bf16; 128k x 64n strip/block
        float (*T)[32][33] = reinterpret_cast<float(*)[32][33]>(smem);
        const int rel = bx0 - 4096;       // 0..4095
        const int e   = rel >> 9;         // 512 blocks/expert
        const int r   = rel & 511;
        const int ks  = r >> 4;           // DF/128 = 32 k-strips
        const int ns  = r & 15;           // DM/64 = 16 n-strips
        transpose_strip128<DF, DM>(W2, w2b, T, e, ks * 128, ns * 64, tid);
    }
}

// -------- grouped expert GEMM (R10 structure, used for GEMM2) ----------------
template<int KD, int ND, bool FIRST, int SPLIT, int NMT, int NT>
__global__ __launch_bounds__(256, 4) void moe_gemm10(
    const ushort* __restrict__ Abuf,
    const ushort* __restrict__ Wb,
    const float* __restrict__ bias,
    const uint32_t* __restrict__ route,
    const uint32_t* __restrict__ cnt,
    const uint32_t* __restrict__ offs,
    const float* __restrict__ prob,
    ushort* __restrict__ hout,
    float* __restrict__ yout)
{
    const int bx0 = blockIdx.x;
    const int cpx = (NEXP * NMT * NT) >> 3;
    const int wk  = (bx0 & 7) * cpx + (bx0 >> 3);
    const int e   = wk / (NMT * NT);
    const int r   = wk % (NMT * NT);
    const int nt  = r / NMT;
    const int mt  = r % NMT;
    const uint32_t cntE = cnt[e];
    const int m0 = mt * 128;
    if ((uint32_t)m0 >= cntE) return;
    const uint32_t hb = offs[e];
    const int n0 = nt * 128;
    const int z  = (SPLIT > 1) ? (int)blockIdx.z : 0;
    const int kbeg = z * (KD / SPLIT);
    const int niter = (KD / SPLIT) / 32;

    __shared__ ushort As[2][128 * 32];
    __shared__ ushort Bs[2][128 * 32];
    __shared__ uint32_t s_route[128];
    __shared__ float s_p[128];

    const int tid = threadIdx.x;
    if (FIRST) {
        if (tid < 128) {
            const uint32_t idx = (uint32_t)(m0 + tid);
            const uint32_t s = (idx < cntE) ? route[e * T_TOKENS + idx] : 0u;
            s_route[tid] = s;
            s_p[tid] = prob[s];
        }
        __syncthreads();
    }

    const int w = tid >> 6, l = tid & 63;
    const ushort* asrc[2];
    const ushort* bsrc[2];
#pragma unroll
    for (int i = 0; i < 2; ++i) {
        const int chunk = (w * 2 + i) * 64 + l;
        const int row = chunk >> 2;
        const int c   = chunk & 3;
        const int cs  = c ^ ((row >> 1) & 3);
        size_t arow;
        if (FIRST) arow = (size_t)(s_route[row] >> 1);
        else       arow = (size_t)(hb + m0 + row);
        asrc[i] = Abuf + arow * KD + cs * 8 + kbeg;
        bsrc[i] = Wb + ((size_t)e * ND + n0 + row) * KD + cs * 8 + kbeg;
    }

    f32x4 acc[4][4];
#pragma unroll
    for (int i = 0; i < 4; ++i)
#pragma unroll
        for (int j = 0; j < 4; ++j) acc[i][j] = (f32x4){0.f, 0.f, 0.f, 0.f};

    const int q = l & 15, g = l >> 4;
    const int wm = w >> 1, wn = w & 1;
    int aoff[4], boff[4];
#pragma unroll
    for (int mi = 0; mi < 4; ++mi) {
        int row = wm * 64 + mi * 16 + q;
        aoff[mi] = row * 64 + (g ^ ((row >> 1) & 3)) * 16;
        row = wn * 64 + mi * 16 + q;
        boff[mi] = row * 64 + (g ^ ((row >> 1) & 3)) * 16;
    }

    ushort* const abase0 = &As[0][0];
    ushort* const bbase0 = &Bs[0][0];

#pragma unroll
    for (int i = 0; i < 2; ++i) gload16(asrc[i], abase0 + (w * 2 + i) * 512);
#pragma unroll
    for (int i = 0; i < 2; ++i) gload16(bsrc[i], bbase0 + (w * 2 + i) * 512);

    int cur = 0;
    for (int t = 0; t < niter; ++t) {
        if (t + 1 < niter) {
            ushort* ad = abase0 + (cur ^ 1) * (128 * 32) + (w * 2) * 512;
            ushort* bd = bbase0 + (cur ^ 1) * (128 * 32) + (w * 2) * 512;
            const int k1 = (t + 1) * 32;
#pragma unroll
            for (int i = 0; i < 2; ++i) gload16(asrc[i] + k1, ad + i * 512);
#pragma unroll
            for (int i = 0; i < 2; ++i) gload16(bsrc[i] + k1, bd + i * 512);
            asm volatile("s_waitcnt vmcnt(4)" ::: "memory");
        } else {
            asm volatile("s_waitcnt vmcnt(0)" ::: "memory");
        }
        __builtin_amdgcn_s_barrier();
        __builtin_amdgcn_sched_barrier(0);

        const char* Ab = (const char*)(abase0 + cur * (128 * 32));
        const char* Bb = (const char*)(bbase0 + cur * (128 * 32));
        bf16x8 af[4], bv[4];
#pragma unroll
        for (int mi = 0; mi < 4; ++mi)
            af[mi] = *reinterpret_cast<const bf16x8*>(Ab + aoff[mi]);
#pragma unroll
        for (int ni = 0; ni < 4; ++ni)
            bv[ni] = *reinterpret_cast<const bf16x8*>(Bb + boff[ni]);
        __builtin_amdgcn_s_setprio(1);
#pragma unroll
        for (int mi = 0; mi < 4; ++mi)
#pragma unroll
            for (int ni = 0; ni < 4; ++ni)
                acc[mi][ni] = __builtin_amdgcn_mfma_f32_16x16x32_bf16(
                    af[mi], bv[ni], acc[mi][ni], 0, 0, 0);
        __builtin_amdgcn_s_setprio(0);
        __builtin_amdgcn_s_barrier();
        cur ^= 1;
    }

#pragma unroll
    for (int mi = 0; mi < 4; ++mi) {
#pragma unroll
        for (int ni = 0; ni < 4; ++ni) {
            const int gcol = n0 + wn * 64 + ni * 16 + q;
#pragma unroll
            for (int j = 0; j < 4; ++j) {
                const int row = wm * 64 + mi * 16 + g * 4 + j;
                if ((uint32_t)(m0 + row) < cntE) {
                    const size_t grow = (size_t)(hb + m0 + row);
                    if (FIRST) {
                        float v = acc[mi][ni][j] + bias[e * ND + gcol];
                        v = fmaxf(v, 0.f) * s_p[row];
                        hout[grow * ND + gcol] = f2bf(v);
                    } else {
                        yout[((size_t)z * NSLOTS + grow) * ND + gcol] = acc[mi][ni][j];
                    }
                }
            }
        }
    }
}

// ------- combine: out[t] = p0*b2[e0] + p1*b2[e1] + sum_z (yc[z][r0]+yc[z][r1])
__global__ __launch_bounds__(256) void combine5(
    const float* __restrict__ yc, const uint32_t* __restrict__ epk,
    const uint32_t* __restrict__ offs, const float* __restrict__ prob,
    const float* __restrict__ b2, float* __restrict__ out)
{
    const int gid = blockIdx.x * 256 + threadIdx.x;
    const int t = gid >> 8;
    const int dq = gid & 255;
    const uint32_t p0 = epk[2 * t], p1 = epk[2 * t + 1];
    const uint32_t e0 = p0 >> 16, e1 = p1 >> 16;
    const uint32_t r0 = offs[e0] + (p0 & 0xFFFFu);
    const uint32_t r1 = offs[e1] + (p1 & 0xFFFFu);
    const float w0 = prob[2 * t], w1 = prob[2 * t + 1];
    const float4 bb0 = reinterpret_cast<const float4*>(b2 + (size_t)e0 * DM)[dq];
    const float4 bb1 = reinterpret_cast<const float4*>(b2 + (size_t)e1 * DM)[dq];
    float4 o = { w0 * bb0.x + w1 * bb1.x, w0 * bb0.y + w1 * bb1.y,
                 w0 * bb0.z + w1 * bb1.z, w0 * bb0.w + w1 * bb1.w };
    const float4* Y = reinterpret_cast<const float4*>(yc);
#pragma unroll
    for (int zz = 0; zz < 4; ++zz) {
        const float4 a = Y[((size_t)zz * NSLOTS + r0) * 256 + dq];
        const float4 b = Y[((size_t)zz * NSLOTS + r1) * 256 + dq];
        o.x += a.x + b.x; o.y += a.y + b.y; o.z += a.z + b.z; o.w += a.w + b.w;
    }
    reinterpret_cast<float4*>(out)[gid] = o;
}

// ================= fallback path (round-1, works in ~55 MB ws) =================
__global__ __launch_bounds__(256) void gate_route_fb(
    const float* __restrict__ x, const float* __restrict__ gw,
    const float* __restrict__ gb,
    uint32_t* __restrict__ route, uint32_t* __restrict__ cnt,
    float* __restrict__ prob)
{
    const int w = threadIdx.x >> 6;
    const int lane = threadIdx.x & 63;
    const int t = blockIdx.x * 4 + w;
    float acc[NEXP];
#pragma unroll
    for (int e = 0; e < NEXP; ++e) acc[e] = 0.f;
    const float* xr = x + (size_t)t * DM;
#pragma unroll
    for (int j = 0; j < DM / 64; ++j) {
        const int d = j * 64 + lane;
        const float xv = xr[d];
        const float* g = gw + (size_t)d * NEXP;
#pragma unroll
        for (int e = 0; e < NEXP; ++e) acc[e] += xv * g[e];
    }
#pragma unroll
    for (int e = 0; e < NEXP; ++e) {
#pragma unroll
        for (int off = 32; off > 0; off >>= 1)
            acc[e] += __shfl_xor(acc[e], off);
        acc[e] += gb[e];
    }
    if (lane == 0) {
        int e0 = 0; float v0 = acc[0];
#pragma unroll
        for (int e = 1; e < NEXP; ++e) if (acc[e] > v0) { v0 = acc[e]; e0 = e; }
        int e1 = -1; float v1 = -1e30f;
#pragma unroll
        for (int e = 0; e < NEXP; ++e) if (e != e0 && acc[e] > v1) { v1 = acc[e]; e1 = e; }
        const float ex = expf(v1 - v0);
        const float inv = 1.f / (1.f + ex);
        prob[t * 2 + 0] = inv;
        prob[t * 2 + 1] = ex * inv;
        uint32_t pos = atomicAdd(&cnt[e0], 1u);
        route[e0 * T_TOKENS + pos] = (uint32_t)(t * 2);
        pos = atomicAdd(&cnt[e1], 1u);
        route[e1 * T_TOKENS + pos] = (uint32_t)(t * 2 + 1);
    }
}

__global__ __launch_bounds__(256) void convert_x_fb(const float* __restrict__ x,
                                                    ushort* __restrict__ xb)
{
    const int i = (blockIdx.x * 256 + threadIdx.x) * 4;
    const float4 v = *reinterpret_cast<const float4*>(x + i);
    ushort4 o;
    o.x = f2bf(v.x); o.y = f2bf(v.y); o.z = f2bf(v.z); o.w = f2bf(v.w);
    *reinterpret_cast<ushort4*>(xb + i) = o;
}

template<int KD, int ND, bool FIRST>
__global__ __launch_bounds__(256) void moe_gemm_v1(
    const ushort* __restrict__ Abuf, const float* __restrict__ W,
    const float* __restrict__ bias, const uint32_t* __restrict__ route,
    const uint32_t* __restrict__ cnt, const float* __restrict__ prob,
    ushort* __restrict__ hout, float* __restrict__ yout)
{
    const int e = blockIdx.x >> 4;
    const int mt = blockIdx.x & 15;
    const uint32_t cntE = cnt[e];
    const int m0 = mt * 128;
    if ((uint32_t)m0 >= cntE) return;
    const int n0 = blockIdx.y * 128;
    const int tid = threadIdx.x;
    __shared__ ushort Asm[128][40];
    __shared__ ushort Bsm[128][40];
    __shared__ uint32_t s_route[128];
    if (tid < 128) {
        const uint32_t idx = (uint32_t)(m0 + tid);
        s_route[tid] = (idx < cntE) ? route[e * T_TOKENS + idx] : 0xFFFFFFFFu;
    }
    __syncthreads();
    const int ar = tid >> 1, ah = tid & 1;
    const uint32_t s_a = s_route[ar];
    size_t arow = 0;
    if (s_a != 0xFFFFFFFFu) arow = FIRST ? (size_t)(s_a >> 1) : (size_t)s_a;
    const ushort* asrc = Abuf + arow * KD + ah * 16;
    const int c4 = tid & 31, kq = tid >> 5;
    const float* wbase = W + (size_t)e * KD * ND + (size_t)n0 + (size_t)c4 * 4;
    f32x4 acc[4][4];
#pragma unroll
    for (int i = 0; i < 4; ++i)
#pragma unroll
        for (int j = 0; j < 4; ++j) acc[i][j] = (f32x4){0.f, 0.f, 0.f, 0.f};
    const int lane = tid & 63, wv = tid >> 6;
    const int wm = wv >> 1, wn = wv & 1;
    const int q = lane & 15, g = lane >> 4;
    for (int k0 = 0; k0 < KD; k0 += 32) {
        {
            const uint4* src = reinterpret_cast<const uint4*>(asrc + k0);
            const uint4 v0 = src[0];
            const uint4 v1 = src[1];
            *reinterpret_cast<uint4*>(&Asm[ar][ah * 16]) = v0;
            *reinterpret_cast<uint4*>(&Asm[ar][ah * 16 + 8]) = v1;
        }
        {
            ushort vals[4][4];
#pragma unroll
            for (int r = 0; r < 4; ++r) {
                const float4 v = *reinterpret_cast<const float4*>(
                    wbase + (size_t)(k0 + kq * 4 + r) * ND);
                vals[r][0] = f2bf(v.x); vals[r][1] = f2bf(v.y);
                vals[r][2] = f2bf(v.z); vals[r][3] = f2bf(v.w);
            }
#pragma unroll
            for (int c = 0; c < 4; ++c) {
                const ushort4 o = { vals[0][c], vals[1][c], vals[2][c], vals[3][c] };
                *reinterpret_cast<ushort4*>(&Bsm[c4 * 4 + c][kq * 4]) = o;
            }
        }
        __syncthreads();
        bf16x8 af[4], bfr[4];
#pragma unroll
        for (int mi = 0; mi < 4; ++mi)
            af[mi] = *reinterpret_cast<const bf16x8*>(&Asm[wm * 64 + mi * 16 + q][g * 8]);
#pragma unroll
        for (int ni = 0; ni < 4; ++ni)
            bfr[ni] = *reinterpret_cast<const bf16x8*>(&Bsm[wn * 64 + ni * 16 + q][g * 8]);
#pragma unroll
        for (int mi = 0; mi < 4; ++mi)
#pragma unroll
            for (int ni = 0; ni < 4; ++ni)
                acc[mi][ni] = __builtin_amdgcn_mfma_f32_16x16x32_bf16(
                    af[mi], bfr[ni], acc[mi][ni], 0, 0, 0);
        __syncthreads();
    }
#pragma unroll
    for (int mi = 0; mi < 4; ++mi) {
#pragma unroll
        for (int ni = 0; ni < 4; ++ni) {
            const int gcol = n0 + wn * 64 + ni * 16 + q;
#pragma unroll
            for (int j = 0; j < 4; ++j) {
                const int row = wm * 64 + mi * 16 + g * 4 + j;
                if ((uint32_t)(m0 + row) < cntE) {
                    const uint32_t s = s_route[row];
                    float v = acc[mi][ni][j] + bias[e * ND + gcol];
                    if (FIRST) {
                        v = fmaxf(v, 0.f);
                        hout[(size_t)s * ND + gcol] = f2bf(v);
                    } else {
                        yout[(size_t)s * ND + gcol] = v * prob[s];
                    }
                }
            }
        }
    }
}

__global__ __launch_bounds__(256) void combine1(const float* __restrict__ yc,
                                                float* __restrict__ out)
{
    const int gid = blockIdx.x * 256 + threadIdx.x;
    const int t = gid >> 8;
    const int dq = gid & 255;
    const float4 va = reinterpret_cast<const float4*>(yc)[(size_t)(2 * t) * 256 + dq];
    const float4 vb = reinterpret_cast<const float4*>(yc)[(size_t)(2 * t + 1) * 256 + dq];
    const float4 o = { va.x + vb.x, va.y + vb.y, va.z + vb.z, va.w + vb.w };
    reinterpret_cast<float4*>(out)[gid] = o;
}

// ---------------- launch ----------------
extern "C" void kernel_launch(void* const* d_in, const int* in_sizes, int n_in,
                              void* d_out, int out_size, void* d_ws, size_t ws_size,
                              hipStream_t stream)
{
    const float* x  = (const float*)d_in[0];
    const float* gw = (const float*)d_in[1];
    const float* gb = (const float*)d_in[2];
    const float* W1 = (const float*)d_in[3];
    const float* b1 = (const float*)d_in[4];
    const float* W2 = (const float*)d_in[5];
    const float* b2 = (const float*)d_in[6];
    float* out = (float*)d_out;
    char* ws = (char*)d_ws;

    // ---- big layout (~168 MB; yc aliases w1b which is dead after GEMM1) ----
    const size_t OFF_XB    = 0;                        // 4 MiB
    const size_t OFF_H     = 4194304;                  // (NSLOTS+128)*4096*2
    const size_t OFF_ROUTE = 38797312;                 // 64 KiB
    const size_t OFF_CNT   = 38862848;                 // 64 B
    const size_t OFF_OFFS  = 38862912;                 // 64 B
    const size_t OFF_PROB  = 38862976;                 // 16 KiB
    const size_t OFF_EPK   = 38879360;                 // 16 KiB
    const size_t OFF_W1B   = 41943040;                 // 64 MiB (aliased by yc)
    const size_t OFF_W2B   = 109051904;                // 64 MiB
    const size_t OFF_YC    = OFF_W1B;                  // 64 MiB (4 z-splits)
    const size_t NEED      = 176160768ull;

    if (ws_size >= NEED) {
        ushort*   xb    = (ushort*)(ws + OFF_XB);
        ushort*   h     = (ushort*)(ws + OFF_H);
        float*    yc    = (float*)(ws + OFF_YC);
        uint32_t* route = (uint32_t*)(ws + OFF_ROUTE);
        uint32_t* cnt   = (uint32_t*)(ws + OFF_CNT);
        uint32_t* offs  = (uint32_t*)(ws + OFF_OFFS);
        float*    prob  = (float*)(ws + OFF_PROB);
        uint32_t* epk   = (uint32_t*)(ws + OFF_EPK);
        ushort*   w1b   = (ushort*)(ws + OFF_W1B);
        ushort*   w2b   = (ushort*)(ws + OFF_W2B);

        hipLaunchKernelGGL(init_cnt, dim3(1), dim3(64), 0, stream, cnt);
        // fused prep: gate_route (512) | convert_x (2048) | trW1 (4096)
        hipLaunchKernelGGL(prep_kernel, dim3(512 + 2048 + 4096), dim3(256), 0, stream,
                           x, gw, gb, W1, route, cnt, prob, epk, xb, w1b);
        hipLaunchKernelGGL(prefix_offs, dim3(1), dim3(64), 0, stream, cnt, offs);
        // fused: GEMM1 (4096, XCD-swizzled) | trW2 (4096)
        hipLaunchKernelGGL(gemm1_trw2, dim3(4096 + 4096), dim3(256), 0, stream,
                           xb, w1b, b1, route, cnt, offs, prob, h, W2, w2b);
        // GEMM2: 128x128, split-K=4, NMT=16, NT=8; yc aliases w1b (dead now)
        hipLaunchKernelGGL((moe_gemm10<DF, DM, false, 4, 16, 8>),
                           dim3(NEXP * 16 * 8, 1, 4), dim3(256), 0, stream,
                           h, w2b, (const float*)nullptr, route, cnt, offs,
                           (const float*)nullptr, (ushort*)nullptr, yc);
        hipLaunchKernelGGL(combine5, dim3(T_TOKENS * DM / 1024), dim3(256), 0, stream,
                           yc, epk, offs, prob, b2, out);
    } else {
        // ---- fallback: round-1 layout (~55 MB) ----
        const size_t F_XB = 0, F_H = 4194304, F_YC = 37748736;
        const size_t F_ROUTE = 54525952, F_CNT = 54591488, F_PROB = 54591552;
        ushort*   xb    = (ushort*)(ws + F_XB);
        ushort*   h     = (ushort*)(ws + F_H);
        float*    yc    = (float*)(ws + F_YC);
        uint32_t* route = (uint32_t*)(ws + F_ROUTE);
        uint32_t* cnt   = (uint32_t*)(ws + F_CNT);
        float*    prob  = (float*)(ws + F_PROB);

        hipLaunchKernelGGL(init_cnt, dim3(1), dim3(64), 0, stream, cnt);
        hipLaunchKernelGGL(gate_route_fb, dim3(T_TOKENS / 4), dim3(256), 0, stream,
                           x, gw, gb, route, cnt, prob);
        hipLaunchKernelGGL(convert_x_fb, dim3(T_TOKENS * DM / 1024), dim3(256), 0, stream, x, xb);
        hipLaunchKernelGGL((moe_gemm_v1<DM, DF, true>), dim3(NEXP * 16, DF / 128),
                           dim3(256), 0, stream, xb, W1, b1, route, cnt, prob,
                           h, (float*)nullptr);
        hipLaunchKernelGGL((moe_gemm_v1<DF, DM, false>), dim3(NEXP * 16, DM / 128),
                           dim3(256), 0, stream, h, W2, b2, route, cnt, prob,
                           (ushort*)nullptr, yc);
        hipLaunchKernelGGL(combine1, dim3(T_TOKENS * DM / 1024), dim3(256), 0, stream, yc, out);
    }
}

// Round 16
// 272.707 us; speedup vs baseline: 1.2400x; 1.0104x over previous
//
#include <hip/hip_runtime.h>
#include <stdint.h>

#define T_TOKENS 2048
#define DM 1024
#define DF 4096
#define NEXP 8
#define NSLOTS (T_TOKENS * 2)

typedef __bf16 bf16x8 __attribute__((ext_vector_type(8)));
typedef float f32x4 __attribute__((ext_vector_type(4)));

__device__ __forceinline__ ushort f2bf(float f) {
    union { float f; uint32_t u; } v; v.f = f;
    uint32_t r = v.u + 0x7FFFu + ((v.u >> 16) & 1u);
    return (ushort)(r >> 16);
}

__device__ __forceinline__ void gload16(const ushort* g, ushort* l) {
    __builtin_amdgcn_global_load_lds(
        (const __attribute__((address_space(1))) uint32_t*)g,
        (__attribute__((address_space(3))) uint32_t*)l,
        16, 0, 0);
}

// ---- transpose: 128k x 64n strip per block, 8x [32][33] fp32 micro-tiles ----
template<int K, int N>
__device__ __forceinline__ void transpose_strip128(
    const float* __restrict__ W, ushort* __restrict__ Wb,
    float (*T)[32][33], int e, int k0, int n0, int tid)
{
    float4 v[8];
#pragma unroll
    for (int p = 0; p < 8; ++p) {
        const int k = p * 16 + (tid >> 4);
        const int n4 = (tid & 15) * 4;
        v[p] = *reinterpret_cast<const float4*>(
            W + ((size_t)e * K + k0 + k) * N + n0 + n4);
    }
#pragma unroll
    for (int p = 0; p < 8; ++p) {
        const int k = p * 16 + (tid >> 4);
        const int n4 = (tid & 15) * 4;
        const int mt = ((k >> 5) << 1) | (n4 >> 5);
        float* dst = &T[mt][k & 31][n4 & 31];
        dst[0] = v[p].x; dst[1] = v[p].y; dst[2] = v[p].z; dst[3] = v[p].w;
    }
    __syncthreads();
#pragma unroll
    for (int p = 0; p < 4; ++p) {
        const int u = p * 256 + tid;
        const int n = u >> 4;              // 0..63
        const int k8 = (u & 15) * 8;       // 0..120
        union { ushort us[8]; uint4 v4; } o;
#pragma unroll
        for (int i = 0; i < 8; ++i) {
            const int k = k8 + i;
            const int mt = ((k >> 5) << 1) | (n >> 5);
            o.us[i] = f2bf(T[mt][k & 31][n & 31]);
        }
        *reinterpret_cast<uint4*>(
            Wb + ((size_t)e * N + n0 + n) * K + k0 + k8) = o.v4;
    }
}

// ---------------- init: zero expert counters ----------------
__global__ void init_cnt(uint32_t* cnt) {
    if (threadIdx.x < NEXP) cnt[threadIdx.x] = 0;
}

// ---------------- exclusive prefix over the 8 counts ----------------
__global__ void prefix_offs(const uint32_t* __restrict__ cnt,
                            uint32_t* __restrict__ offs)
{
    if (threadIdx.x == 0) {
        uint32_t a = 0;
#pragma unroll
        for (int e = 0; e < NEXP; ++e) { offs[e] = a; a += cnt[e]; }
        offs[NEXP] = a;
    }
}

// == prep: gate_route [0,512) | convert_x [512,2560) | trW1 [2560,6656) =======
// trW1 supertiled: inner-64 = 8 ks x 8 nsl -> the ~concurrent 64-block group
// covers ALL k (full 2KB w1b-row writes) and 2KB-contiguous W1-row reads.
__global__ __launch_bounds__(256) void prep_kernel(
    const float* __restrict__ x, const float* __restrict__ gw,
    const float* __restrict__ gb, const float* __restrict__ W1,
    uint32_t* __restrict__ route, uint32_t* __restrict__ cnt,
    float* __restrict__ prob, uint32_t* __restrict__ epk,
    ushort* __restrict__ xb, ushort* __restrict__ w1b)
{
    __shared__ float T[8][32][33];
    const int bx = blockIdx.x;
    const int tid = threadIdx.x;

    if (bx < 512) {
        // ---- gate + route: one wave per token ----
        const int w = tid >> 6;
        const int lane = tid & 63;
        const int t = bx * 4 + w;
        float acc[NEXP];
#pragma unroll
        for (int e = 0; e < NEXP; ++e) acc[e] = 0.f;
        const float* xr = x + (size_t)t * DM;
#pragma unroll
        for (int j = 0; j < DM / 64; ++j) {
            const int d = j * 64 + lane;
            const float xv = xr[d];
            const float* g = gw + (size_t)d * NEXP;
#pragma unroll
            for (int e = 0; e < NEXP; ++e) acc[e] += xv * g[e];
        }
#pragma unroll
        for (int e = 0; e < NEXP; ++e) {
#pragma unroll
            for (int off = 32; off > 0; off >>= 1)
                acc[e] += __shfl_xor(acc[e], off);
            acc[e] += gb[e];
        }
        if (lane == 0) {
            int e0 = 0; float v0 = acc[0];
#pragma unroll
            for (int e = 1; e < NEXP; ++e) if (acc[e] > v0) { v0 = acc[e]; e0 = e; }
            int e1 = -1; float v1 = -1e30f;
#pragma unroll
            for (int e = 0; e < NEXP; ++e) if (e != e0 && acc[e] > v1) { v1 = acc[e]; e1 = e; }
            const float ex = expf(v1 - v0);
            const float inv = 1.f / (1.f + ex);
            prob[t * 2 + 0] = inv;
            prob[t * 2 + 1] = ex * inv;
            uint32_t pos = atomicAdd(&cnt[e0], 1u);
            route[e0 * T_TOKENS + pos] = (uint32_t)(t * 2);
            epk[t * 2] = ((uint32_t)e0 << 16) | pos;
            pos = atomicAdd(&cnt[e1], 1u);
            route[e1 * T_TOKENS + pos] = (uint32_t)(t * 2 + 1);
            epk[t * 2 + 1] = ((uint32_t)e1 << 16) | pos;
        }
    } else if (bx < 2560) {
        // ---- x fp32 -> bf16 ----
        const int i = ((bx - 512) * 256 + tid) * 4;
        const float4 v = *reinterpret_cast<const float4*>(x + i);
        ushort4 o;
        o.x = f2bf(v.x); o.y = f2bf(v.y); o.z = f2bf(v.z); o.w = f2bf(v.w);
        *reinterpret_cast<ushort4*>(xb + i) = o;
    } else {
        // ---- W1 [E][DM][DF] -> w1b [E][DF][DM]; supertiled ordering
        const int rel = bx - 2560;        // 0..4095
        const int e   = rel >> 9;         // 512 blocks/expert
        const int r   = rel & 511;
        const int nsg = r >> 6;           // 8 n-supergroups
        const int inr = r & 63;
        const int ks  = inr >> 3;         // 8 k-strips (fast)
        const int nsl = inr & 7;          // 8 n-strips within group (fastest)
        const int ns  = nsg * 8 + nsl;
        transpose_strip128<DM, DF>(W1, w1b, T, e, ks * 128, ns * 64, tid);
    }
}

// ====== fused GEMM1 [0,4096) + transpose W2 [4096,8192) ======================
// GEMM1 branch byte-identical to R10's moe_gemm10: 128x128, BK=32 dbuf,
// chunk-XOR swizzle, counted vmcnt(4), XCD-chunked swizzle.
// trW2 supertiled: inner-128 = 32 ks x 4 nsl -> full 8KB w2b-row writes,
// 1KB-contiguous W2-row reads.
__global__ __launch_bounds__(256, 4) void gemm1_trw2(
    const ushort* __restrict__ xb, const ushort* __restrict__ w1b,
    const float* __restrict__ b1, const uint32_t* __restrict__ route,
    const uint32_t* __restrict__ cnt, const uint32_t* __restrict__ offs,
    const float* __restrict__ prob, ushort* __restrict__ hout,
    const float* __restrict__ W2, ushort* __restrict__ w2b)
{
    __shared__ __attribute__((aligned(16))) char smem[33792];
    const int bx0 = blockIdx.x;
    const int tid = threadIdx.x;

    if (bx0 < 4096) {
        // -------- GEMM1 (KD=DM, ND=DF, NMT=16, NT=32) --------
        ushort* Asm = (ushort*)smem;                       // [2][128*32] 16KB
        ushort* Bsm = (ushort*)(smem + 16384);             // [2][128*32] 16KB
        uint32_t* s_route = (uint32_t*)(smem + 32768);     // 512B
        float* s_p = (float*)(smem + 33280);               // 512B

        const int cpx = (NEXP * 16 * 32) >> 3;             // 512
        const int wk  = (bx0 & 7) * cpx + (bx0 >> 3);
        const int e   = wk / (16 * 32);
        const int r   = wk % (16 * 32);
        const int nt  = r / 16;
        const int mt  = r % 16;
        const uint32_t cntE = cnt[e];
        const int m0 = mt * 128;
        if ((uint32_t)m0 >= cntE) return;
        const uint32_t hb = offs[e];
        const int n0 = nt * 128;
        const int niter = DM / 32;

        if (tid < 128) {
            const uint32_t idx = (uint32_t)(m0 + tid);
            const uint32_t s = (idx < cntE) ? route[e * T_TOKENS + idx] : 0u;
            s_route[tid] = s;
            s_p[tid] = prob[s];
        }
        __syncthreads();

        const int w = tid >> 6, l = tid & 63;
        const ushort* asrc[2];
        const ushort* bsrc[2];
#pragma unroll
        for (int i = 0; i < 2; ++i) {
            const int chunk = (w * 2 + i) * 64 + l;
            const int row = chunk >> 2;
            const int c   = chunk & 3;
            const int cs  = c ^ ((row >> 1) & 3);
            const size_t arow = (size_t)(s_route[row] >> 1);
            asrc[i] = xb + arow * DM + cs * 8;
            bsrc[i] = w1b + ((size_t)e * DF + n0 + row) * DM + cs * 8;
        }

        f32x4 acc[4][4];
#pragma unroll
        for (int i = 0; i < 4; ++i)
#pragma unroll
            for (int j = 0; j < 4; ++j) acc[i][j] = (f32x4){0.f, 0.f, 0.f, 0.f};

        const int q = l & 15, g = l >> 4;
        const int wm = w >> 1, wn = w & 1;
        int aoff[4], boff[4];
#pragma unroll
        for (int mi = 0; mi < 4; ++mi) {
            int row = wm * 64 + mi * 16 + q;
            aoff[mi] = row * 64 + (g ^ ((row >> 1) & 3)) * 16;
            row = wn * 64 + mi * 16 + q;
            boff[mi] = row * 64 + (g ^ ((row >> 1) & 3)) * 16;
        }

#pragma unroll
        for (int i = 0; i < 2; ++i) gload16(asrc[i], Asm + (w * 2 + i) * 512);
#pragma unroll
        for (int i = 0; i < 2; ++i) gload16(bsrc[i], Bsm + (w * 2 + i) * 512);

        int cur = 0;
        for (int t = 0; t < niter; ++t) {
            if (t + 1 < niter) {
                ushort* ad = Asm + (cur ^ 1) * (128 * 32) + (w * 2) * 512;
                ushort* bd = Bsm + (cur ^ 1) * (128 * 32) + (w * 2) * 512;
                const int k1 = (t + 1) * 32;
#pragma unroll
                for (int i = 0; i < 2; ++i) gload16(asrc[i] + k1, ad + i * 512);
#pragma unroll
                for (int i = 0; i < 2; ++i) gload16(bsrc[i] + k1, bd + i * 512);
                asm volatile("s_waitcnt vmcnt(4)" ::: "memory");
            } else {
                asm volatile("s_waitcnt vmcnt(0)" ::: "memory");
            }
            __builtin_amdgcn_s_barrier();
            __builtin_amdgcn_sched_barrier(0);

            const char* Ab = (const char*)(Asm + cur * (128 * 32));
            const char* Bb = (const char*)(Bsm + cur * (128 * 32));
            bf16x8 af[4], bv[4];
#pragma unroll
            for (int mi = 0; mi < 4; ++mi)
                af[mi] = *reinterpret_cast<const bf16x8*>(Ab + aoff[mi]);
#pragma unroll
            for (int ni = 0; ni < 4; ++ni)
                bv[ni] = *reinterpret_cast<const bf16x8*>(Bb + boff[ni]);
            __builtin_amdgcn_s_setprio(1);
#pragma unroll
            for (int mi = 0; mi < 4; ++mi)
#pragma unroll
                for (int ni = 0; ni < 4; ++ni)
                    acc[mi][ni] = __builtin_amdgcn_mfma_f32_16x16x32_bf16(
                        af[mi], bv[ni], acc[mi][ni], 0, 0, 0);
            __builtin_amdgcn_s_setprio(0);
            __builtin_amdgcn_s_barrier();
            cur ^= 1;
        }

#pragma unroll
        for (int mi = 0; mi < 4; ++mi) {
#pragma unroll
            for (int ni = 0; ni < 4; ++ni) {
                const int gcol = n0 + wn * 64 + ni * 16 + q;
#pragma unroll
                for (int j = 0; j < 4; ++j) {
                    const int row = wm * 64 + mi * 16 + g * 4 + j;
                    if ((uint32_t)(m0 + row) < cntE) {
                        const size_t grow = (size_t)(hb + m0 + row);
                        float v = acc[mi][ni][j] + b1[e * DF + gcol];
                        v = fmaxf(v, 0.f) * s_p[row];
                        hout[grow * DF + gcol] = f2bf(v);
                    }
                }
            }
        }
    } else {
        // ---- W2 [E][DF][DM] -> w2b [E][DM][DF]; supertiled ordering
        float (*T)[32][33] = reinterpret_cast<float(*)[32][33]>(smem);
        const int rel = bx0 - 4096;       // 0..4095
        const int e   = rel >> 9;         // 512 blocks/expert
        const int r   = rel & 511;
        const int nsg = r >> 7;           // 4 n-supergroups
        const int inr = r & 127;
        const int ks  = inr >> 2;         // 32 k-strips (fast)
        const int nsl = inr & 3;          // 4 n-strips (fastest)
        const int ns  = nsg * 4 + nsl;
        transpose_strip128<DF, DM>(W2, w2b, T, e, ks * 128, ns * 64, tid);
    }
}

// -------- grouped expert GEMM (R10 structure, used for GEMM2) ----------------
template<int KD, int ND, bool FIRST, int SPLIT, int NMT, int NT>
__global__ __launch_bounds__(256, 4) void moe_gemm10(
    const ushort* __restrict__ Abuf,
    const ushort* __restrict__ Wb,
    const float* __restrict__ bias,
    const uint32_t* __restrict__ route,
    const uint32_t* __restrict__ cnt,
    const uint32_t* __restrict__ offs,
    const float* __restrict__ prob,
    ushort* __restrict__ hout,
    float* __restrict__ yout)
{
    const int bx0 = blockIdx.x;
    const int cpx = (NEXP * NMT * NT) >> 3;
    const int wk  = (bx0 & 7) * cpx + (bx0 >> 3);
    const int e   = wk / (NMT * NT);
    const int r   = wk % (NMT * NT);
    const int nt  = r / NMT;
    const int mt  = r % NMT;
    const uint32_t cntE = cnt[e];
    const int m0 = mt * 128;
    if ((uint32_t)m0 >= cntE) return;
    const uint32_t hb = offs[e];
    const int n0 = nt * 128;
    const int z  = (SPLIT > 1) ? (int)blockIdx.z : 0;
    const int kbeg = z * (KD / SPLIT);
    const int niter = (KD / SPLIT) / 32;

    __shared__ ushort As[2][128 * 32];
    __shared__ ushort Bs[2][128 * 32];
    __shared__ uint32_t s_route[128];
    __shared__ float s_p[128];

    const int tid = threadIdx.x;
    if (FIRST) {
        if (tid < 128) {
            const uint32_t idx = (uint32_t)(m0 + tid);
            const uint32_t s = (idx < cntE) ? route[e * T_TOKENS + idx] : 0u;
            s_route[tid] = s;
            s_p[tid] = prob[s];
        }
        __syncthreads();
    }

    const int w = tid >> 6, l = tid & 63;
    const ushort* asrc[2];
    const ushort* bsrc[2];
#pragma unroll
    for (int i = 0; i < 2; ++i) {
        const int chunk = (w * 2 + i) * 64 + l;
        const int row = chunk >> 2;
        const int c   = chunk & 3;
        const int cs  = c ^ ((row >> 1) & 3);
        size_t arow;
        if (FIRST) arow = (size_t)(s_route[row] >> 1);
        else       arow = (size_t)(hb + m0 + row);
        asrc[i] = Abuf + arow * KD + cs * 8 + kbeg;
        bsrc[i] = Wb + ((size_t)e * ND + n0 + row) * KD + cs * 8 + kbeg;
    }

    f32x4 acc[4][4];
#pragma unroll
    for (int i = 0; i < 4; ++i)
#pragma unroll
        for (int j = 0; j < 4; ++j) acc[i][j] = (f32x4){0.f, 0.f, 0.f, 0.f};

    const int q = l & 15, g = l >> 4;
    const int wm = w >> 1, wn = w & 1;
    int aoff[4], boff[4];
#pragma unroll
    for (int mi = 0; mi < 4; ++mi) {
        int row = wm * 64 + mi * 16 + q;
        aoff[mi] = row * 64 + (g ^ ((row >> 1) & 3)) * 16;
        row = wn * 64 + mi * 16 + q;
        boff[mi] = row * 64 + (g ^ ((row >> 1) & 3)) * 16;
    }

    ushort* const abase0 = &As[0][0];
    ushort* const bbase0 = &Bs[0][0];

#pragma unroll
    for (int i = 0; i < 2; ++i) gload16(asrc[i], abase0 + (w * 2 + i) * 512);
#pragma unroll
    for (int i = 0; i < 2; ++i) gload16(bsrc[i], bbase0 + (w * 2 + i) * 512);

    int cur = 0;
    for (int t = 0; t < niter; ++t) {
        if (t + 1 < niter) {
            ushort* ad = abase0 + (cur ^ 1) * (128 * 32) + (w * 2) * 512;
            ushort* bd = bbase0 + (cur ^ 1) * (128 * 32) + (w * 2) * 512;
            const int k1 = (t + 1) * 32;
#pragma unroll
            for (int i = 0; i < 2; ++i) gload16(asrc[i] + k1, ad + i * 512);
#pragma unroll
            for (int i = 0; i < 2; ++i) gload16(bsrc[i] + k1, bd + i * 512);
            asm volatile("s_waitcnt vmcnt(4)" ::: "memory");
        } else {
            asm volatile("s_waitcnt vmcnt(0)" ::: "memory");
        }
        __builtin_amdgcn_s_barrier();
        __builtin_amdgcn_sched_barrier(0);

        const char* Ab = (const char*)(abase0 + cur * (128 * 32));
        const char* Bb = (const char*)(bbase0 + cur * (128 * 32));
        bf16x8 af[4], bv[4];
#pragma unroll
        for (int mi = 0; mi < 4; ++mi)
            af[mi] = *reinterpret_cast<const bf16x8*>(Ab + aoff[mi]);
#pragma unroll
        for (int ni = 0; ni < 4; ++ni)
            bv[ni] = *reinterpret_cast<const bf16x8*>(Bb + boff[ni]);
        __builtin_amdgcn_s_setprio(1);
#pragma unroll
        for (int mi = 0; mi < 4; ++mi)
#pragma unroll
            for (int ni = 0; ni < 4; ++ni)
                acc[mi][ni] = __builtin_amdgcn_mfma_f32_16x16x32_bf16(
                    af[mi], bv[ni], acc[mi][ni], 0, 0, 0);
        __builtin_amdgcn_s_setprio(0);
        __builtin_amdgcn_s_barrier();
        cur ^= 1;
    }

#pragma unroll
    for (int mi = 0; mi < 4; ++mi) {
#pragma unroll
        for (int ni = 0; ni < 4; ++ni) {
            const int gcol = n0 + wn * 64 + ni * 16 + q;
#pragma unroll
            for (int j = 0; j < 4; ++j) {
                const int row = wm * 64 + mi * 16 + g * 4 + j;
                if ((uint32_t)(m0 + row) < cntE) {
                    const size_t grow = (size_t)(hb + m0 + row);
                    if (FIRST) {
                        float v = acc[mi][ni][j] + bias[e * ND + gcol];
                        v = fmaxf(v, 0.f) * s_p[row];
                        hout[grow * ND + gcol] = f2bf(v);
                    } else {
                        yout[((size_t)z * NSLOTS + grow) * ND + gcol] = acc[mi][ni][j];
                    }
                }
            }
        }
    }
}

// ------- combine: out[t] = p0*b2[e0] + p1*b2[e1] + sum_z (yc[z][r0]+yc[z][r1])
template<int SPLIT>
__global__ __launch_bounds__(256) void combine5(
    const float* __restrict__ yc, const uint32_t* __restrict__ epk,
    const uint32_t* __restrict__ offs, const float* __restrict__ prob,
    const float* __restrict__ b2, float* __restrict__ out)
{
    const int gid = blockIdx.x * 256 + threadIdx.x;
    const int t = gid >> 8;
    const int dq = gid & 255;
    const uint32_t p0 = epk[2 * t], p1 = epk[2 * t + 1];
    const uint32_t e0 = p0 >> 16, e1 = p1 >> 16;
    const uint32_t r0 = offs[e0] + (p0 & 0xFFFFu);
    const uint32_t r1 = offs[e1] + (p1 & 0xFFFFu);
    const float w0 = prob[2 * t], w1 = prob[2 * t + 1];
    const float4 bb0 = reinterpret_cast<const float4*>(b2 + (size_t)e0 * DM)[dq];
    const float4 bb1 = reinterpret_cast<const float4*>(b2 + (size_t)e1 * DM)[dq];
    float4 o = { w0 * bb0.x + w1 * bb1.x, w0 * bb0.y + w1 * bb1.y,
                 w0 * bb0.z + w1 * bb1.z, w0 * bb0.w + w1 * bb1.w };
    const float4* Y = reinterpret_cast<const float4*>(yc);
#pragma unroll
    for (int zz = 0; zz < SPLIT; ++zz) {
        const float4 a = Y[((size_t)zz * NSLOTS + r0) * 256 + dq];
        const float4 b = Y[((size_t)zz * NSLOTS + r1) * 256 + dq];
        o.x += a.x + b.x; o.y += a.y + b.y; o.z += a.z + b.z; o.w += a.w + b.w;
    }
    reinterpret_cast<float4*>(out)[gid] = o;
}

// ================= fallback path (round-1, works in ~55 MB ws) =================
__global__ __launch_bounds__(256) void gate_route_fb(
    const float* __restrict__ x, const float* __restrict__ gw,
    const float* __restrict__ gb,
    uint32_t* __restrict__ route, uint32_t* __restrict__ cnt,
    float* __restrict__ prob)
{
    const int w = threadIdx.x >> 6;
    const int lane = threadIdx.x & 63;
    const int t = blockIdx.x * 4 + w;
    float acc[NEXP];
#pragma unroll
    for (int e = 0; e < NEXP; ++e) acc[e] = 0.f;
    const float* xr = x + (size_t)t * DM;
#pragma unroll
    for (int j = 0; j < DM / 64; ++j) {
        const int d = j * 64 + lane;
        const float xv = xr[d];
        const float* g = gw + (size_t)d * NEXP;
#pragma unroll
        for (int e = 0; e < NEXP; ++e) acc[e] += xv * g[e];
    }
#pragma unroll
    for (int e = 0; e < NEXP; ++e) {
#pragma unroll
        for (int off = 32; off > 0; off >>= 1)
            acc[e] += __shfl_xor(acc[e], off);
        acc[e] += gb[e];
    }
    if (lane == 0) {
        int e0 = 0; float v0 = acc[0];
#pragma unroll
        for (int e = 1; e < NEXP; ++e) if (acc[e] > v0) { v0 = acc[e]; e0 = e; }
        int e1 = -1; float v1 = -1e30f;
#pragma unroll
        for (int e = 0; e < NEXP; ++e) if (e != e0 && acc[e] > v1) { v1 = acc[e]; e1 = e; }
        const float ex = expf(v1 - v0);
        const float inv = 1.f / (1.f + ex);
        prob[t * 2 + 0] = inv;
        prob[t * 2 + 1] = ex * inv;
        uint32_t pos = atomicAdd(&cnt[e0], 1u);
        route[e0 * T_TOKENS + pos] = (uint32_t)(t * 2);
        pos = atomicAdd(&cnt[e1], 1u);
        route[e1 * T_TOKENS + pos] = (uint32_t)(t * 2 + 1);
    }
}

__global__ __launch_bounds__(256) void convert_x_fb(const float* __restrict__ x,
                                                    ushort* __restrict__ xb)
{
    const int i = (blockIdx.x * 256 + threadIdx.x) * 4;
    const float4 v = *reinterpret_cast<const float4*>(x + i);
    ushort4 o;
    o.x = f2bf(v.x); o.y = f2bf(v.y); o.z = f2bf(v.z); o.w = f2bf(v.w);
    *reinterpret_cast<ushort4*>(xb + i) = o;
}

template<int KD, int ND, bool FIRST>
__global__ __launch_bounds__(256) void moe_gemm_v1(
    const ushort* __restrict__ Abuf, const float* __restrict__ W,
    const float* __restrict__ bias, const uint32_t* __restrict__ route,
    const uint32_t* __restrict__ cnt, const float* __restrict__ prob,
    ushort* __restrict__ hout, float* __restrict__ yout)
{
    const int e = blockIdx.x >> 4;
    const int mt = blockIdx.x & 15;
    const uint32_t cntE = cnt[e];
    const int m0 = mt * 128;
    if ((uint32_t)m0 >= cntE) return;
    const int n0 = blockIdx.y * 128;
    const int tid = threadIdx.x;
    __shared__ ushort Asm[128][40];
    __shared__ ushort Bsm[128][40];
    __shared__ uint32_t s_route[128];
    if (tid < 128) {
        const uint32_t idx = (uint32_t)(m0 + tid);
        s_route[tid] = (idx < cntE) ? route[e * T_TOKENS + idx] : 0xFFFFFFFFu;
    }
    __syncthreads();
    const int ar = tid >> 1, ah = tid & 1;
    const uint32_t s_a = s_route[ar];
    size_t arow = 0;
    if (s_a != 0xFFFFFFFFu) arow = FIRST ? (size_t)(s_a >> 1) : (size_t)s_a;
    const ushort* asrc = Abuf + arow * KD + ah * 16;
    const int c4 = tid & 31, kq = tid >> 5;
    const float* wbase = W + (size_t)e * KD * ND + (size_t)n0 + (size_t)c4 * 4;
    f32x4 acc[4][4];
#pragma unroll
    for (int i = 0; i < 4; ++i)
#pragma unroll
        for (int j = 0; j < 4; ++j) acc[i][j] = (f32x4){0.f, 0.f, 0.f, 0.f};
    const int lane = tid & 63, wv = tid >> 6;
    const int wm = wv >> 1, wn = wv & 1;
    const int q = lane & 15, g = lane >> 4;
    for (int k0 = 0; k0 < KD; k0 += 32) {
        {
            const uint4* src = reinterpret_cast<const uint4*>(asrc + k0);
            const uint4 v0 = src[0];
            const uint4 v1 = src[1];
            *reinterpret_cast<uint4*>(&Asm[ar][ah * 16]) = v0;
            *reinterpret_cast<uint4*>(&Asm[ar][ah * 16 + 8]) = v1;
        }
        {
            ushort vals[4][4];
#pragma unroll
            for (int r = 0; r < 4; ++r) {
                const float4 v = *reinterpret_cast<const float4*>(
                    wbase + (size_t)(k0 + kq * 4 + r) * ND);
                vals[r][0] = f2bf(v.x); vals[r][1] = f2bf(v.y);
                vals[r][2] = f2bf(v.z); vals[r][3] = f2bf(v.w);
            }
#pragma unroll
            for (int c = 0; c < 4; ++c) {
                const ushort4 o = { vals[0][c], vals[1][c], vals[2][c], vals[3][c] };
                *reinterpret_cast<ushort4*>(&Bsm[c4 * 4 + c][kq * 4]) = o;
            }
        }
        __syncthreads();
        bf16x8 af[4], bfr[4];
#pragma unroll
        for (int mi = 0; mi < 4; ++mi)
            af[mi] = *reinterpret_cast<const bf16x8*>(&Asm[wm * 64 + mi * 16 + q][g * 8]);
#pragma unroll
        for (int ni = 0; ni < 4; ++ni)
            bfr[ni] = *reinterpret_cast<const bf16x8*>(&Bsm[wn * 64 + ni * 16 + q][g * 8]);
#pragma unroll
        for (int mi = 0; mi < 4; ++mi)
#pragma unroll
            for (int ni = 0; ni < 4; ++ni)
                acc[mi][ni] = __builtin_amdgcn_mfma_f32_16x16x32_bf16(
                    af[mi], bfr[ni], acc[mi][ni], 0, 0, 0);
        __syncthreads();
    }
#pragma unroll
    for (int mi = 0; mi < 4; ++mi) {
#pragma unroll
        for (int ni = 0; ni < 4; ++ni) {
            const int gcol = n0 + wn * 64 + ni * 16 + q;
#pragma unroll
            for (int j = 0; j < 4; ++j) {
                const int row = wm * 64 + mi * 16 + g * 4 + j;
                if ((uint32_t)(m0 + row) < cntE) {
                    const uint32_t s = s_route[row];
                    float v = acc[mi][ni][j] + bias[e * ND + gcol];
                    if (FIRST) {
                        v = fmaxf(v, 0.f);
                        hout[(size_t)s * ND + gcol] = f2bf(v);
                    } else {
                        yout[(size_t)s * ND + gcol] = v * prob[s];
                    }
                }
            }
        }
    }
}

__global__ __launch_bounds__(256) void combine1(const float* __restrict__ yc,
                                                float* __restrict__ out)
{
    const int gid = blockIdx.x * 256 + threadIdx.x;
    const int t = gid >> 8;
    const int dq = gid & 255;
    const float4 va = reinterpret_cast<const float4*>(yc)[(size_t)(2 * t) * 256 + dq];
    const float4 vb = reinterpret_cast<const float4*>(yc)[(size_t)(2 * t + 1) * 256 + dq];
    const float4 o = { va.x + vb.x, va.y + vb.y, va.z + vb.z, va.w + vb.w };
    reinterpret_cast<float4*>(out)[gid] = o;
}

// ---------------- launch ----------------
extern "C" void kernel_launch(void* const* d_in, const int* in_sizes, int n_in,
                              void* d_out, int out_size, void* d_ws, size_t ws_size,
                              hipStream_t stream)
{
    const float* x  = (const float*)d_in[0];
    const float* gw = (const float*)d_in[1];
    const float* gb = (const float*)d_in[2];
    const float* W1 = (const float*)d_in[3];
    const float* b1 = (const float*)d_in[4];
    const float* W2 = (const float*)d_in[5];
    const float* b2 = (const float*)d_in[6];
    float* out = (float*)d_out;
    char* ws = (char*)d_ws;

    // ---- big layout (~168 MB; yc aliases w1b which is dead after GEMM1) ----
    const size_t OFF_XB    = 0;                        // 4 MiB
    const size_t OFF_H     = 4194304;                  // (NSLOTS+128)*4096*2
    const size_t OFF_ROUTE = 38797312;                 // 64 KiB
    const size_t OFF_CNT   = 38862848;                 // 64 B
    const size_t OFF_OFFS  = 38862912;                 // 64 B
    const size_t OFF_PROB  = 38862976;                 // 16 KiB
    const size_t OFF_EPK   = 38879360;                 // 16 KiB
    const size_t OFF_W1B   = 41943040;                 // 64 MiB (aliased by yc)
    const size_t OFF_W2B   = 109051904;                // 64 MiB
    const size_t OFF_YC    = OFF_W1B;                  // 32 MB used (2 z-splits)
    const size_t NEED      = 176160768ull;

    if (ws_size >= NEED) {
        ushort*   xb    = (ushort*)(ws + OFF_XB);
        ushort*   h     = (ushort*)(ws + OFF_H);
        float*    yc    = (float*)(ws + OFF_YC);
        uint32_t* route = (uint32_t*)(ws + OFF_ROUTE);
        uint32_t* cnt   = (uint32_t*)(ws + OFF_CNT);
        uint32_t* offs  = (uint32_t*)(ws + OFF_OFFS);
        float*    prob  = (float*)(ws + OFF_PROB);
        uint32_t* epk   = (uint32_t*)(ws + OFF_EPK);
        ushort*   w1b   = (ushort*)(ws + OFF_W1B);
        ushort*   w2b   = (ushort*)(ws + OFF_W2B);

        hipLaunchKernelGGL(init_cnt, dim3(1), dim3(64), 0, stream, cnt);
        // fused prep: gate_route (512) | convert_x (2048) | trW1 (4096, supertiled)
        hipLaunchKernelGGL(prep_kernel, dim3(512 + 2048 + 4096), dim3(256), 0, stream,
                           x, gw, gb, W1, route, cnt, prob, epk, xb, w1b);
        hipLaunchKernelGGL(prefix_offs, dim3(1), dim3(64), 0, stream, cnt, offs);
        // fused: GEMM1 (4096, XCD-swizzled) | trW2 (4096, supertiled)
        hipLaunchKernelGGL(gemm1_trw2, dim3(4096 + 4096), dim3(256), 0, stream,
                           xb, w1b, b1, route, cnt, offs, prob, h, W2, w2b);
        // GEMM2: 128x128, split-K=2, NMT=16, NT=8; yc aliases w1b (dead now)
        hipLaunchKernelGGL((moe_gemm10<DF, DM, false, 2, 16, 8>),
                           dim3(NEXP * 16 * 8, 1, 2), dim3(256), 0, stream,
                           h, w2b, (const float*)nullptr, route, cnt, offs,
                           (const float*)nullptr, (ushort*)nullptr, yc);
        hipLaunchKernelGGL((combine5<2>), dim3(T_TOKENS * DM / 1024), dim3(256), 0, stream,
                           yc, epk, offs, prob, b2, out);
    } else {
        // ---- fallback: round-1 layout (~55 MB) ----
        const size_t F_XB = 0, F_H = 4194304, F_YC = 37748736;
        const size_t F_ROUTE = 54525952, F_CNT = 54591488, F_PROB = 54591552;
        ushort*   xb    = (ushort*)(ws + F_XB);
        ushort*   h     = (ushort*)(ws + F_H);
        float*    yc    = (float*)(ws + F_YC);
        uint32_t* route = (uint32_t*)(ws + F_ROUTE);
        uint32_t* cnt   = (uint32_t*)(ws + F_CNT);
        float*    prob  = (float*)(ws + F_PROB);

        hipLaunchKernelGGL(init_cnt, dim3(1), dim3(64), 0, stream, cnt);
        hipLaunchKernelGGL(gate_route_fb, dim3(T_TOKENS / 4), dim3(256), 0, stream,
                           x, gw, gb, route, cnt, prob);
        hipLaunchKernelGGL(convert_x_fb, dim3(T_TOKENS * DM / 1024), dim3(256), 0, stream, x, xb);
        hipLaunchKernelGGL((moe_gemm_v1<DM, DF, true>), dim3(NEXP * 16, DF / 128),
                           dim3(256), 0, stream, xb, W1, b1, route, cnt, prob,
                           h, (float*)nullptr);
        hipLaunchKernelGGL((moe_gemm_v1<DF, DM, false>), dim3(NEXP * 16, DM / 128),
                           dim3(256), 0, stream, h, W2, b2, route, cnt, prob,
                           (ushort*)nullptr, yc);
        hipLaunchKernelGGL(combine1, dim3(T_TOKENS * DM / 1024), dim3(256), 0, stream, yc, out);
    }
}